// Round 7
// baseline (314.219 us; speedup 1.0000x reference)
//
#include <hip/hip_runtime.h>
#include <stdint.h>
#include <string.h>

typedef unsigned int u32;
typedef unsigned long long u64;

#define B_ 8
#define N_ 100000
#define C_ 10
#define K1_ 1000
#define N2_ (C_ * K1_)
#define NBIN 4096
#define CAP 4096       // fallback / topk2 sort capacity
#define CAP_C 2048     // fast-path candidate capacity per slice
#define SEGROWS 256    // fused-NMS segment rows (fallback path)
#define MIN_CONF_F 0.05f
#define NMS_IOU_F 0.4f
#define POST_IOU_F 0.65f
#define T0_F 0.985f    // conservative fast-path threshold (per-slice count ~1500)

#define TOTAL_F4 (B_ * N_ * C_ / 4)  // 2,000,000 float4s
#define CBLK 512                     // compact blocks
#define LCAP 512                     // per-block candidate capacity (lambda~234, 18 sigma)
#define HDRW 84                      // u32 stride per compact-block header

// split-NMS parameters
#define NTILE 136   // upper-triangular 64x64 tiles of the 1024x1024 pair matrix

static __device__ __forceinline__ u32 next_pow2_ge(u32 x, u32 lo, u32 hi) {
  u32 n = lo;
  while (n < x && n < hi) n <<= 1;
  return n;
}

// triangular tile id of (rt, w), w >= rt
#define TILE_ID(rt, w) ((rt) * 16 - (((rt) * ((rt) - 1)) >> 1) + ((w) - (rt)))

// Prep: one thread writes one corner record (bit-identical FP to the
// validated k_nms_prep body).
static __device__ __forceinline__ void prep_write(const float* __restrict__ bb,
                                                  float s, int oi,
                                                  float4* __restrict__ cor,
                                                  int pos) {
  bool v = (s >= MIN_CONF_F);
  float cx = 0.f, cy = 0.f, w = 0.f, h = 0.f;
  if (v) {
    const float4 bp = *(const float4*)(bb + (size_t)oi * 4);
    cx = bp.x; cy = bp.y; w = bp.z; h = bp.w;
  }
  float y1 = cy - h * 0.5f, x1 = cx - w * 0.5f;
  float y2 = cy + h * 0.5f, x2 = cx + w * 0.5f;
  cor[pos] = make_float4(y1, x1, y2, x2);
}

// Exact threshold predicate, all-f32 (double-float). Reproduces
// (double)inter OP M*(double)den where M = m1+m0 (25-bit midpoint, product
// exact in f64): t+e = m1*den exactly (TwoProdFMA), r = fl(e + m0*den) —
// single rounding preserves sign incl. exact ties; d = inter-t is exact in
// the decision region (Sterbenz). _rn intrinsics pin against fp-contract.
template <bool STRICT>
static __device__ __forceinline__ bool iou_pred(float inter, float den,
                                                float m1, float m0) {
  float t = __fmul_rn(m1, den);
  float e = __builtin_fmaf(m1, den, -t);
  float r = __builtin_fmaf(m0, den, e);
  float d = __fsub_rn(inter, t);
  return STRICT ? (d > r) : (d >= r);
}

// One 64x64 mask tile from LDS-resident corners/areas (validated R14 body).
template <bool STRICT>
static __device__ __forceinline__ void build_tile(const float4* __restrict__ box4,
                                                  const float* __restrict__ area,
                                                  int tt, int lane,
                                                  float m1, float m0,
                                                  u64* __restrict__ mg) {
  int rt = 0, bse = 0;
  while (tt >= bse + (16 - rt)) { bse += 16 - rt; ++rt; }
  const int w = rt + (tt - bse);
  const int row = (rt << 6) | lane;

  const float4 ib = box4[row];
  const float ia = area[row];
  const float4* jcol = &box4[w << 6];
  const float* jarea = &area[w << 6];
  u32 mhi = 0, mlo = 0;
#pragma unroll 8
  for (int j = 63; j >= 32; --j) {
    const float4 jb = jcol[j];
    const float ja = jarea[j];
    float ih = fminf(ib.z, jb.z) - fmaxf(ib.x, jb.x); ih = fmaxf(ih, 0.0f);
    float iw_ = fminf(ib.w, jb.w) - fmaxf(ib.y, jb.y); iw_ = fmaxf(iw_, 0.0f);
    float inter = ih * iw_;
    float den = fmaxf((ia + ja) - inter, 1e-8f);
    bool p_ = iou_pred<STRICT>(inter, den, m1, m0);
    mhi = (mhi << 1) | (p_ ? 1u : 0u);
  }
#pragma unroll 8
  for (int j = 31; j >= 0; --j) {
    const float4 jb = jcol[j];
    const float ja = jarea[j];
    float ih = fminf(ib.z, jb.z) - fmaxf(ib.x, jb.x); ih = fmaxf(ih, 0.0f);
    float iw_ = fminf(ib.w, jb.w) - fmaxf(ib.y, jb.y); iw_ = fmaxf(iw_, 0.0f);
    float inter = ih * iw_;
    float den = fmaxf((ia + ja) - inter, 1e-8f);
    bool p_ = iou_pred<STRICT>(inter, den, m1, m0);
    mlo = (mlo << 1) | (p_ ? 1u : 0u);
  }
  u64 m = ((u64)mhi << 32) | (u64)mlo;
  if (w == rt) m &= (lane == 63) ? 0ull : (~0ull << (lane + 1));
  mg[(tt << 6) + lane] = m;  // coalesced 512-B store
}

// ---------------------------------------------------------------------------
// Wave-synchronous bitonic sort (desc) for 1024 threads. Steps with j <= 64
// stay inside a wave-owned 128-element block -> no barrier (wave64 LDS ops
// complete in order). Barrier only around cross steps (j >= 128).
// ---------------------------------------------------------------------------
__device__ __forceinline__ void bitonic_sort_desc_ws(u64* buf, u32 n, int tid) {
  bool prev_cross = true;  // initial fill was block-wide scattered -> barrier
  for (u32 kk = 2; kk <= n; kk <<= 1) {
    for (u32 j = kk >> 1; j > 0; j >>= 1) {
      const bool cross = (j >= 128);
      if (cross || prev_cross) __syncthreads();
      for (u32 t = (u32)tid; t < (n >> 1); t += 1024) {
        u32 i = ((t & ~(j - 1)) << 1) | (t & (j - 1));
        u32 l = i | j;
        u64 a = buf[i], bb = buf[l];
        bool desc = ((i & kk) == 0);
        if (desc ? (a < bb) : (a > bb)) { buf[i] = bb; buf[l] = a; }
      }
      prev_cross = cross;
    }
  }
  __syncthreads();  // publish: readers read outside their wave's block
}

// ---------------------------------------------------------------------------
// Pass 1 (LDS-staged compaction). Validated R4 body.
// ---------------------------------------------------------------------------
__global__ __launch_bounds__(256) void k_compact(const float* __restrict__ cls,
                                                 u64* __restrict__ cand,
                                                 u32* __restrict__ hdr) {
  __shared__ u32 lcnt[B_ * C_];
  __shared__ u32 lpre[B_ * C_ + 1];
  __shared__ u32 ltot;
  __shared__ u32 lovf;
  __shared__ u64 ekey[LCAP];
  __shared__ u32 emeta[LCAP];  // (slice<<16) | local_rank

  const int tid = threadIdx.x;
  const u32 bk = blockIdx.x;
  if (tid < B_ * C_) lcnt[tid] = 0;
  if (tid == 0) { ltot = 0; lovf = 0; }
  __syncthreads();

  const u32 lo = bk * ((TOTAL_F4 + CBLK - 1) / CBLK);
  u32 hi = lo + ((TOTAL_F4 + CBLK - 1) / CBLK);
  if (hi > TOTAL_F4) hi = TOTAL_F4;

  const float4* p4 = (const float4*)cls;
  for (u32 f = lo + tid; f < hi; f += 256) {
    float4 v = p4[f];
    u32 e = f * 4u;
    float vs[4] = {v.x, v.y, v.z, v.w};
#pragma unroll
    for (int j = 0; j < 4; ++j) {
      float s = vs[j];
      if (s >= T0_F) {
        u32 g = e + (u32)j;           // flat index into (B,N,C)
        u32 gi = g / (u32)C_;         // b*N + i
        u32 c = g - gi * (u32)C_;
        u32 bi = gi / (u32)N_;
        u32 i = gi - bi * (u32)N_;
        u32 slice = bi * (u32)C_ + c;
        u32 rank = atomicAdd(&lcnt[slice], 1u);
        u32 pos = atomicAdd(&ltot, 1u);
        if (pos < LCAP) {
          ekey[pos] = ((u64)__float_as_uint(s) << 32) | (u32)(~i);
          emeta[pos] = (slice << 16) | rank;
        } else {
          lovf = 1;
        }
      }
    }
  }
  __syncthreads();

  // exclusive prefix of lcnt -> lpre[0..80] (Hillis-Steele, 7 steps)
  if (tid < B_ * C_) lpre[tid + 1] = lcnt[tid];
  if (tid == 0) lpre[0] = 0;
  __syncthreads();
  for (int off = 1; off < B_ * C_; off <<= 1) {
    u32 v = 0;
    const bool act = (tid >= off && tid <= B_ * C_);
    if (act) v = lpre[tid - off];
    __syncthreads();
    if (act) lpre[tid] += v;
    __syncthreads();
  }

  // scatter into slice-grouped segment
  u32 tot = ltot;
  if (tot > LCAP) tot = LCAP;
  u64* seg = cand + (size_t)bk * LCAP;
  for (u32 p = tid; p < tot; p += 256) {
    u32 mta = emeta[p];
    u32 slice = mta >> 16;
    u32 rank = mta & 0xFFFFu;
    u32 dst = lpre[slice] + rank;
    if (dst < LCAP) seg[dst] = ekey[p];  // garbage on ovf; sel ignores then
  }
  if (tid <= B_ * C_) hdr[bk * HDRW + tid] = lpre[tid];
  if (tid == 0) hdr[bk * HDRW + 81] = lovf;
}

// ---------------------------------------------------------------------------
// Pass 2: gather per-slice candidates, wave-sync bitonic sort, emit top 1000.
// Register-resident header combine (2 barriers). Exact histogram fallback
// inlined (statistically dead); prep fused as epilogue. Validated R6 body.
// ---------------------------------------------------------------------------
__global__ __launch_bounds__(1024) void k_sel(const float* __restrict__ cls,
                                              const u64* __restrict__ cand,
                                              const u32* __restrict__ hdr,
                                              float* __restrict__ score1,
                                              int* __restrict__ idx1,
                                              const float* __restrict__ boxes,
                                              float4* __restrict__ cor1,
                                              int do_prep) {
  const int slice = blockIdx.x;
  const int tid = threadIdx.x;
  const int bd = 1024;
  const int lane = tid & 63, wv = tid >> 6;

  __shared__ u32 hist[NBIN];  // fallback histogram only
  __shared__ u64 buf[CAP];
  __shared__ u32 wsum[8];
  __shared__ int sh_b1;
  __shared__ u32 sh_base, sh_T, sh_cnt, sh_ovf;

  if (tid == 0) sh_ovf = 0;
  __syncthreads();

  u32 mycnt = 0, mystart = 0, incl = 0;
  if (tid < CBLK) {
    const u32* h = hdr + (size_t)tid * HDRW;
    u32 a = h[slice], b2 = h[slice + 1];
    mystart = a;
    mycnt = b2 - a;
    if (h[81]) sh_ovf = 1;
    incl = mycnt;
    for (int off = 1; off < 64; off <<= 1) {
      u32 v = (u32)__shfl_up((int)incl, off, 64);
      if (lane >= off) incl += v;
    }
    if (lane == 63) wsum[wv] = incl;
  }
  __syncthreads();

  u32 wbase = 0, m = 0;
#pragma unroll
  for (int w2 = 0; w2 < 8; ++w2) {
    u32 v = wsum[w2];
    if (w2 < wv) wbase += v;
    m += v;
  }
  const bool fast = (sh_ovf == 0) && m >= (u32)K1_ && m <= (u32)CAP_C;

  if (fast) {
    if (tid < CBLK) {
      u32 base = wbase + incl - mycnt;  // exclusive prefix
      const u64* src = cand + (size_t)tid * LCAP + mystart;
      for (u32 r = 0; r < mycnt; ++r) buf[base + r] = src[r];
    }
    const u32 nn = next_pow2_ge(m, 1024u, (u32)CAP_C);
    for (u32 i2 = (u32)tid; i2 < nn; i2 += bd)
      if (i2 >= m) buf[i2] = 0ull;  // disjoint from gather region: no barrier
    bitonic_sort_desc_ws(buf, nn, tid);

    float os = -1.0f; int ooi = 0;
    if (tid < K1_) {
      u64 e = buf[tid];
      u32 k = (u32)(e >> 32);
      os = __uint_as_float(k);     // fast path: k != 0 always (s >= T0)
      ooi = (int)(~(u32)e);
      score1[slice * K1_ + tid] = os;
      idx1[slice * K1_ + tid] = ooi;
    }
    if (do_prep)
      prep_write(boxes + (size_t)(slice / C_) * N_ * 4, os, ooi, cor1,
                 (slice << 10) + tid);
    return;
  }

  // ---- exact fallback: two-level histogram select over the full column ----
  const int b = slice / C_, c = slice % C_;

  for (int i = tid; i < NBIN; i += bd) hist[i] = 0;
  __syncthreads();
  for (int i = tid; i < N_; i += bd) {
    float s = cls[((size_t)b * N_ + i) * C_ + c];
    if (s >= MIN_CONF_F) atomicAdd(&hist[__float_as_uint(s) >> 19], 1u);
  }
  __syncthreads();
  if (tid == 0) {
    u32 cum = 0; int b1 = -1; u32 base = 0;
    for (int bin = NBIN - 1; bin >= 0; --bin) {
      cum += hist[bin];
      if (cum >= (u32)K1_) { b1 = bin; base = cum - hist[bin]; break; }
    }
    sh_b1 = b1; sh_base = base;
    if (b1 < 0) sh_T = 0;
  }
  __syncthreads();
  const int b1 = sh_b1;

  if (b1 >= 0) {
    const u32 base = sh_base;
    for (int i = tid; i < NBIN; i += bd) hist[i] = 0;
    __syncthreads();
    for (int i = tid; i < N_; i += bd) {
      float s = cls[((size_t)b * N_ + i) * C_ + c];
      if (s >= MIN_CONF_F) {
        u32 k = __float_as_uint(s);
        if ((int)(k >> 19) == b1) atomicAdd(&hist[(k >> 7) & 0xFFFu], 1u);
      }
    }
    __syncthreads();
    if (tid == 0) {
      u32 cum = base;
      u32 T = ((u32)b1) << 19;
      for (int bin = NBIN - 1; bin >= 0; --bin) {
        cum += hist[bin];
        if (cum >= (u32)K1_) { T = (((u32)b1) << 19) | (((u32)bin) << 7); break; }
      }
      sh_T = T;
    }
    __syncthreads();
  }

  if (tid == 0) sh_cnt = 0;
  __syncthreads();
  const u32 T = sh_T;
  for (int i = tid; i < N_; i += bd) {
    float s = cls[((size_t)b * N_ + i) * C_ + c];
    if (s >= MIN_CONF_F) {
      u32 k = __float_as_uint(s);
      if (k >= T) {
        u32 pos = atomicAdd(&sh_cnt, 1u);
        if (pos < CAP) buf[pos] = ((u64)k << 32) | (u32)(~(u32)i);
      }
    }
  }
  __syncthreads();
  u32 mm = sh_cnt; if (mm > CAP) mm = CAP;
  for (int i = tid; i < CAP; i += bd)
    if ((u32)i >= mm) buf[i] = 0ull;
  __syncthreads();

  for (u32 kk = 2; kk <= CAP; kk <<= 1) {
    for (u32 j = kk >> 1; j > 0; j >>= 1) {
      for (u32 i = tid; i < CAP; i += bd) {
        u32 l = i ^ j;
        if (l > i) {
          u64 a = buf[i], bb2 = buf[l];
          bool desc = ((i & kk) == 0);
          if (desc ? (a < bb2) : (a > bb2)) { buf[i] = bb2; buf[l] = a; }
        }
      }
      __syncthreads();
    }
  }

  float os = -1.0f; int ooi = 0;
  if (tid < K1_) {
    u64 e = buf[tid];
    u32 k = (u32)(e >> 32);
    if (k != 0) { os = __uint_as_float(k); ooi = (int)(~(u32)e); }
    score1[slice * K1_ + tid] = os;
    idx1[slice * K1_ + tid] = ooi;
  }
  if (do_prep)
    prep_write(boxes + (size_t)(slice / C_) * N_ * 4, os, ooi, cor1,
               (slice << 10) + tid);
}

// Hierarchical scan core (rolled, O(1) registers). Exact greedy keep set.
__device__ void scan_core(const u64* __restrict__ mg, float s,
                          u64* __restrict__ keepb) {
  const int tid = threadIdx.x, wv = tid >> 6, lane = tid & 63;
  const u64 myvalid = __ballot(s >= MIN_CONF_F);

  u64 ext_partial = 0;

#pragma unroll 1
  for (int g = 0; g < 16; ++g) {
    u64 Tg = 0ull;
    if (g <= wv) Tg = mg[(TILE_ID(g, wv) << 6) + lane];
    const u64 nz = __ballot(Tg != 0ull);  // suppressor rows in this tile
    if (wv == g) {
      u64 ext = ext_partial;
      for (int off = 1; off < 64; off <<= 1) {
        u32 lo = (u32)__shfl_xor((int)(u32)ext, off, 64);
        u32 hi = (u32)__shfl_xor((int)(u32)(ext >> 32), off, 64);
        ext |= ((u64)hi << 32) | lo;
      }
      const u32 tlo = (u32)Tg, thi = (u32)(Tg >> 32);
      u64 rem = myvalid & ~ext;
      u64 cand = rem & nz;
      while (cand) {
        int i = __ffsll((long long)cand) - 1;
        cand &= cand - 1;  // clear bit i
        if ((rem >> i) & 1ull) {
          u32 rlo = __builtin_amdgcn_readlane(tlo, i);
          u32 rhi = __builtin_amdgcn_readlane(thi, i);
          u64 row = ((u64)rhi << 32) | rlo;  // bits only > i (diag-masked)
          rem &= ~row;
          cand &= ~row;
        }
      }
      if (lane == 0) keepb[g] = rem;
    }
    __syncthreads();
    if (wv > g) {
      u64 kg = keepb[g];  // broadcast LDS read
      if ((kg >> lane) & 1ull) ext_partial |= Tg;
    }
  }
}

// ===========================================================================
// Fused pass-1 NMS: one block per slice. Stage corners once (1024 threads),
// build all 136 tiles with 16 waves into mask1 (global), barrier (same-CU
// R-after-W coherent), hierarchical scan, write keep1. Bodies verbatim.
// ===========================================================================
template <bool STRICT>
__global__ __launch_bounds__(1024) void k_nms1f(const float4* __restrict__ cor,
                                                const float* __restrict__ score1,
                                                float m1, float m0,
                                                u64* __restrict__ maskg,
                                                int* __restrict__ keep1) {
  __shared__ float4 box4[1024];
  __shared__ float area[1024];
  __shared__ u64 keepb[16];
  const int slice = blockIdx.x;
  const int tid = threadIdx.x, wave = tid >> 6, lane = tid & 63;

  {
    const float4 c = cor[(slice << 10) + tid];
    box4[tid] = c;
    area[tid] = (c.z - c.x) * (c.w - c.y);
  }
  __syncthreads();

  u64* mg = maskg + (size_t)slice * (NTILE * 64);
  for (int tt = wave; tt < NTILE; tt += 16)
    build_tile<STRICT>(box4, area, tt, lane, m1, m0, mg);
  __syncthreads();

  float s = (tid < K1_) ? score1[slice * K1_ + tid] : -1.0f;
  scan_core(mg, s, keepb);
  __syncthreads();
  if (tid < K1_)
    keep1[slice * K1_ + tid] = (int)((keepb[tid >> 6] >> (tid & 63)) & 1ull);
}

// ---------------------------------------------------------------------------
// Parallel boundary-bin select over a 4096-bin LDS histogram (1024 threads).
// Wave-shuffle suffix scan + 16 wave totals (2 barriers). Validated R6 body.
// ---------------------------------------------------------------------------
__device__ __forceinline__ void suffix_select(const u32* __restrict__ hist,
                                              u32* __restrict__ wtot,  // [16]
                                              u32 base, u32 K,
                                              int* out_bin, u32* out_next) {
  const int t = threadIdx.x;  // 1024
  const int lane = t & 63, wv = t >> 6;
  u32 h0 = hist[4 * t], h1 = hist[4 * t + 1];
  u32 h2 = hist[4 * t + 2], h3 = hist[4 * t + 3];
  const u32 own = h0 + h1 + h2 + h3;
  u32 suf = own;
  for (int off = 1; off < 64; off <<= 1) {
    u32 v = (u32)__shfl_down((int)suf, off, 64);
    if (lane + off < 64) suf += v;
  }
  if (lane == 0) wtot[wv] = suf;
  __syncthreads();
  u32 upw = 0;
#pragma unroll
  for (int w2 = 0; w2 < 16; ++w2) {
    u32 v = wtot[w2];
    if (w2 > wv) upw += v;
  }
  if (t == 0 && base + (suf + upw) < K) { *out_bin = -1; *out_next = base; }
  u32 up = suf - own + upw;  // = aux[t+1]
  u32 s3 = h3 + up;
  u32 s2 = h2 + s3;
  u32 s1 = h1 + s2;
  u32 s0 = h0 + s1;
  u32 c0 = base + s0, c1 = base + s1, c2 = base + s2, c3 = base + s3;
  u32 c4 = base + up;
  if (c0 >= K && c1 < K) { *out_bin = 4 * t;     *out_next = c1; }
  if (c1 >= K && c2 < K) { *out_bin = 4 * t + 1; *out_next = c2; }
  if (c2 >= K && c3 < K) { *out_bin = 4 * t + 2; *out_next = c3; }
  if (c3 >= K && c4 < K) { *out_bin = 4 * t + 3; *out_next = c4; }
  __syncthreads();
}

// ===========================================================================
// Fused final kernel: per-batch top-1000 (validated histogram + wave-sync
// bitonic) -> winners + corners to LDS -> build 136 tiles into mask2 ->
// hierarchical scan -> ordered output. One 8-block launch replaces
// topk2 + build2 + scan2 (block b produces everything batch b needs).
// ===========================================================================
template <bool STRICT>
__global__ __launch_bounds__(1024) void k_final(const float* __restrict__ score1,
                                                const int* __restrict__ idx1,
                                                const int* __restrict__ keep1,
                                                const float* __restrict__ boxes,
                                                float m1, float m0,
                                                u64* __restrict__ maskg,
                                                float* __restrict__ out) {
  const int b = blockIdx.x;
  const int tid = threadIdx.x, wave = tid >> 6, lane = tid & 63;

  __shared__ union U {
    struct { u32 hist[NBIN]; u32 wtot[16]; u64 buf[CAP]; } a;
    struct { float4 box4[1024]; float area[1024];
             float sscore[K1_]; int scls[K1_]; int sorig[K1_];
             u64 keepb[16]; short ord[K1_]; int lbase[17]; } c;
  } sh;
  __shared__ int sh_bin;
  __shared__ u32 sh_next, sh_T, sh_cnt;
  __shared__ int sh_ordc;

  // ---- phase A: per-batch top-1000 (verbatim k_topk2 select) ----
  for (int i = tid; i < NBIN; i += 1024) sh.a.hist[i] = 0;
  __syncthreads();
  for (int f = tid; f < N2_; f += 1024) {
    if (keep1[b * N2_ + f])
      atomicAdd(&sh.a.hist[__float_as_uint(score1[b * N2_ + f]) >> 19], 1u);
  }
  __syncthreads();
  suffix_select(sh.a.hist, sh.a.wtot, 0u, (u32)K1_, &sh_bin, &sh_next);
  const int b1 = sh_bin;
  const u32 base = sh_next;

  if (b1 >= 0) {
    for (int i = tid; i < NBIN; i += 1024) sh.a.hist[i] = 0;
    if (tid == 0) sh_bin = -2;
    __syncthreads();
    for (int f = tid; f < N2_; f += 1024) {
      if (keep1[b * N2_ + f]) {
        u32 k = __float_as_uint(score1[b * N2_ + f]);
        if ((int)(k >> 19) == b1) atomicAdd(&sh.a.hist[(k >> 7) & 0xFFFu], 1u);
      }
    }
    __syncthreads();
    suffix_select(sh.a.hist, sh.a.wtot, base, (u32)K1_, &sh_bin, &sh_next);
    if (tid == 0) {
      int b2 = sh_bin;
      sh_T = (b2 >= 0) ? ((((u32)b1) << 19) | (((u32)b2) << 7))
                       : (((u32)b1) << 19);
    }
  } else {
    if (tid == 0) sh_T = 0;
  }
  if (tid == 0) sh_cnt = 0;
  __syncthreads();

  const u32 T = sh_T;
  for (int f = tid; f < N2_; f += 1024) {
    if (keep1[b * N2_ + f]) {
      u32 k = __float_as_uint(score1[b * N2_ + f]);
      if (k >= T) {
        u32 pos = atomicAdd(&sh_cnt, 1u);
        if (pos < CAP) sh.a.buf[pos] = ((u64)k << 32) | (u32)(~(u32)f);
      }
    }
  }
  __syncthreads();
  u32 m = sh_cnt; if (m > CAP) m = CAP;
  const u32 n = next_pow2_ge(m, 1024u, (u32)CAP);
  for (u32 i = tid; i < n; i += 1024)
    if (i >= m) sh.a.buf[i] = 0ull;
  bitonic_sort_desc_ws(sh.a.buf, n, tid);  // opens and closes with barriers

  // decode winner into registers (verbatim k_topk2 epilogue values)
  float os = -1.0f; int ocls = 0, oorig = 0;
  if (tid < K1_) {
    u64 e = sh.a.buf[tid];
    u32 k = (u32)(e >> 32);
    if (k != 0) {
      os = __uint_as_float(k);
      u32 f = ~(u32)e;
      ocls = (int)(f / K1_);
      int slot = (int)(f - (u32)ocls * K1_);
      oorig = idx1[(b * C_ + ocls) * K1_ + slot];
    }
  }
  __syncthreads();  // all buf reads complete before union repurpose

  // ---- phase B: winners + corners into LDS (bit-identical prep math) ----
  if (tid < K1_) {
    sh.c.sscore[tid] = os;
    sh.c.scls[tid] = ocls;
    sh.c.sorig[tid] = oorig;
  }
  {
    bool v = (os >= MIN_CONF_F);   // os = -1 for tid >= K1_
    float cx = 0.f, cy = 0.f, w = 0.f, h = 0.f;
    if (v) {
      const float4 bp =
          *(const float4*)(boxes + ((size_t)b * N_ + oorig) * 4);
      cx = bp.x; cy = bp.y; w = bp.z; h = bp.w;
    }
    float y1 = cy - h * 0.5f, x1 = cx - w * 0.5f;
    float y2 = cy + h * 0.5f, x2 = cx + w * 0.5f;
    sh.c.box4[tid] = make_float4(y1, x1, y2, x2);
    sh.c.area[tid] = (y2 - y1) * (x2 - x1);
  }
  __syncthreads();

  // ---- phase C: build 136 tiles into mask2, then hierarchical scan ----
  u64* mg = maskg + (size_t)b * (NTILE * 64);
  for (int tt = wave; tt < NTILE; tt += 16)
    build_tile<STRICT>(sh.c.box4, sh.c.area, tt, lane, m1, m0, mg);
  __syncthreads();

  scan_core(mg, os, sh.c.keepb);
  __syncthreads();

  // ---- phase D: ordered output (verbatim k_nms_scan2 epilogue) ----
  if (tid == 0) {
    int acc = 0;
    for (int wdx = 0; wdx < 16; ++wdx) {
      sh.c.lbase[wdx] = acc;
      acc += __popcll(sh.c.keepb[wdx]);
    }
    sh.c.lbase[16] = acc;
    sh_ordc = acc;
  }
  __syncthreads();
  if (tid < 16) {
    u64 mm2 = sh.c.keepb[tid];
    int bse = sh.c.lbase[tid];
    while (mm2) {
      int bit = __ffsll((long long)mm2) - 1;
      sh.c.ord[bse++] = (short)((tid << 6) | bit);
      mm2 &= mm2 - 1;
    }
  }
  __syncthreads();

  for (int t = tid; t < K1_ * 6; t += 1024) out[(size_t)b * K1_ * 6 + t] = 0.0f;
  __syncthreads();

  const int cnt = sh_ordc;
  for (int q = tid; q < cnt; q += 1024) {
    int p = sh.c.ord[q];
    int oi = sh.c.sorig[p];
    const float4 bp = *(const float4*)(boxes + ((size_t)b * N_ + oi) * 4);
    float* o = out + ((size_t)b * K1_ + q) * 6;
    o[0] = bp.x; o[1] = bp.y; o[2] = bp.z; o[3] = bp.w;
    o[4] = (float)sh.c.scls[p];
    o[5] = sh.c.sscore[p];
  }
}

// ===========================================================================
// Fallback path (ws too small) — validated R8 fused NMS + R6 topk2, verbatim.
// ===========================================================================
__device__ __forceinline__ void nms_run(const float* __restrict__ scores,
                                        const int* __restrict__ origs,
                                        const float* __restrict__ boxesB,
                                        float thr,
                                        float4* box4, float* area,
                                        u64* mask, u64* validw, u64* keepw) {
  const int tid = threadIdx.x;
  const int wave = tid >> 6, lane = tid & 63;

  {
    const int p = tid;
    float s = (p < K1_) ? scores[p] : -1.0f;
    bool v = (s >= MIN_CONF_F);
    float cx = 0.f, cy = 0.f, w = 0.f, h = 0.f;
    if (v) {
      const float4 bp = *(const float4*)(boxesB + (size_t)origs[p] * 4);
      cx = bp.x; cy = bp.y; w = bp.z; h = bp.w;
    }
    float y1 = cy - h * 0.5f, x1 = cx - w * 0.5f;
    float y2 = cy + h * 0.5f, x2 = cx + w * 0.5f;
    box4[p] = make_float4(y1, x1, y2, x2);
    area[p] = (y2 - y1) * (x2 - x1);
    u64 mb = __ballot(v);
    if (lane == 0) validw[wave] = mb;
  }
  __syncthreads();

  const float cf = thr;
  const float cnext = __uint_as_float(__float_as_uint(cf) + 1u);
  const double M = ((double)cf + (double)cnext) * 0.5;
  const bool strict = ((__float_as_uint(cf) & 1u) == 0u);

  const int ss = wave & 3, qq = wave >> 2;
  int col;
  if (qq == 0) col = ss;
  else if (qq == 1) col = 7 - ss;
  else if (qq == 2) col = 8 + ss;
  else col = 15 - ss;

  u64 vw = validw[tid & 15];
  u64 supp = 0;

  for (int seg = 0; seg < 4; ++seg) {
    const int ibase = seg * SEGROWS;
    const int lim = (K1_ - ibase < SEGROWS) ? (K1_ - ibase) : SEGROWS;
    const int rtg0 = ibase >> 6;
    int ntile = col - rtg0 + 1;
    if (ntile < 0) ntile = 0;
    if (ntile > 4) ntile = 4;

    if (ntile > 0) {
      float4 ib[4];
      float ia[4];
#pragma unroll
      for (int r = 0; r < 4; ++r) {
        if (r < ntile) {
          const int i = ibase + (r << 6) + lane;
          ib[r] = box4[i];
          ia[r] = area[i];
        }
      }
      u32 mhi[4] = {0, 0, 0, 0}, mlo[4] = {0, 0, 0, 0};
      const float4* jcol = &box4[col << 6];

      for (int j = 63; j >= 32; --j) {
        const float4 jb = jcol[j];
        const float ja = (jb.z - jb.x) * (jb.w - jb.y);
#pragma unroll
        for (int r = 0; r < 4; ++r) {
          if (r < ntile) {
            float ih = fminf(ib[r].z, jb.z) - fmaxf(ib[r].x, jb.x);
            ih = fmaxf(ih, 0.0f);
            float iw_ = fminf(ib[r].w, jb.w) - fmaxf(ib[r].y, jb.y);
            iw_ = fmaxf(iw_, 0.0f);
            float inter = ih * iw_;
            float den = fmaxf((ia[r] + ja) - inter, 1e-8f);
            bool p_ = strict ? ((double)inter > M * (double)den)
                             : ((double)inter >= M * (double)den);
            mhi[r] = (mhi[r] << 1) | (p_ ? 1u : 0u);
          }
        }
      }
      for (int j = 31; j >= 0; --j) {
        const float4 jb = jcol[j];
        const float ja = (jb.z - jb.x) * (jb.w - jb.y);
#pragma unroll
        for (int r = 0; r < 4; ++r) {
          if (r < ntile) {
            float ih = fminf(ib[r].z, jb.z) - fmaxf(ib[r].x, jb.x);
            ih = fmaxf(ih, 0.0f);
            float iw_ = fminf(ib[r].w, jb.w) - fmaxf(ib[r].y, jb.y);
            iw_ = fmaxf(iw_, 0.0f);
            float inter = ih * iw_;
            float den = fmaxf((ia[r] + ja) - inter, 1e-8f);
            bool p_ = strict ? ((double)inter > M * (double)den)
                             : ((double)inter >= M * (double)den);
            mlo[r] = (mlo[r] << 1) | (p_ ? 1u : 0u);
          }
        }
      }
#pragma unroll
      for (int r = 0; r < 4; ++r) {
        if (r < ntile) {
          u64 m = ((u64)mhi[r] << 32) | (u64)mlo[r];
          if (rtg0 + r == col)
            m &= (lane == 63) ? 0ull : (~0ull << (lane + 1));
          const int il = (r << 6) | lane;
          mask[il * 16 + (col ^ (il & 15))] = m;
        }
      }
    }
    __syncthreads();

    if (tid < 64) {
      const int l = tid & 15;
      u64 r0 = 0, r1 = 0, r2 = 0, r3 = 0;
      if (l >= ((ibase + 0) >> 6)) r0 = mask[0 * 16 + (l ^ 0)];
      if (l >= ((ibase + 1) >> 6)) r1 = mask[1 * 16 + (l ^ 1)];
      if (l >= ((ibase + 2) >> 6)) r2 = mask[2 * 16 + (l ^ 2)];
      if (l >= ((ibase + 3) >> 6)) r3 = mask[3 * 16 + (l ^ 3)];
      for (int il = 0; il < lim; il += 4) {
        const int i0 = ibase + il;
        const int n0 = (il + 4 < lim) ? il + 4 : il;
        const int n1 = (il + 5 < lim) ? il + 5 : il;
        const int n2 = (il + 6 < lim) ? il + 6 : il;
        const int n3 = (il + 7 < lim) ? il + 7 : il;
        u64 m0 = r0, m1 = r1, m2 = r2, m3 = r3;
        r0 = (l >= ((ibase + n0) >> 6)) ? mask[n0 * 16 + (l ^ (n0 & 15))] : 0ull;
        r1 = (l >= ((ibase + n1) >> 6)) ? mask[n1 * 16 + (l ^ (n1 & 15))] : 0ull;
        r2 = (l >= ((ibase + n2) >> 6)) ? mask[n2 * 16 + (l ^ (n2 & 15))] : 0ull;
        r3 = (l >= ((ibase + n3) >> 6)) ? mask[n3 * 16 + (l ^ (n3 & 15))] : 0ull;
        bool a;
        a = (tid == (i0 >> 6)) && (((vw & ~supp) >> (i0 & 63)) & 1ull);
        if (__any(a)) supp |= m0;
        a = (tid == ((i0 + 1) >> 6)) && (((vw & ~supp) >> ((i0 + 1) & 63)) & 1ull);
        if (__any(a)) supp |= m1;
        a = (tid == ((i0 + 2) >> 6)) && (((vw & ~supp) >> ((i0 + 2) & 63)) & 1ull);
        if (__any(a)) supp |= m2;
        a = (tid == ((i0 + 3) >> 6)) && (((vw & ~supp) >> ((i0 + 3) & 63)) & 1ull);
        if (__any(a)) supp |= m3;
      }
    }
    __syncthreads();
  }

  if (tid < 16) keepw[tid] = vw & ~supp;
}

__global__ __launch_bounds__(1024) void k_nms1(const float* __restrict__ boxes,
                                               const float* __restrict__ score1,
                                               const int* __restrict__ idx1,
                                               int* __restrict__ keep1) {
  __shared__ float4 box4[1024];
  __shared__ float area[1024];
  __shared__ u64 mask[SEGROWS * 16];
  __shared__ u64 validw[16], keepw[16];

  const int slice = blockIdx.x;
  const int b = slice / C_;
  nms_run(score1 + slice * K1_, idx1 + slice * K1_,
          boxes + (size_t)b * N_ * 4, NMS_IOU_F,
          box4, area, mask, validw, keepw);
  __syncthreads();

  const int p = threadIdx.x;
  if (p < K1_)
    keep1[slice * K1_ + p] = (int)((keepw[p >> 6] >> (p & 63)) & 1ull);
}

__global__ __launch_bounds__(1024) void k_topk2(const float* __restrict__ score1,
                                                const int* __restrict__ idx1,
                                                const int* __restrict__ keep1,
                                                float* __restrict__ sel_score,
                                                int* __restrict__ sel_cls,
                                                int* __restrict__ sel_orig) {
  const int b = blockIdx.x;
  const int tid = threadIdx.x;

  __shared__ u32 hist[NBIN];
  __shared__ u32 wtot[16];
  __shared__ u64 buf[CAP];
  __shared__ int sh_bin;
  __shared__ u32 sh_next;
  __shared__ u32 sh_T, sh_cnt;

  for (int i = tid; i < NBIN; i += 1024) hist[i] = 0;
  __syncthreads();
  for (int f = tid; f < N2_; f += 1024) {
    if (keep1[b * N2_ + f])
      atomicAdd(&hist[__float_as_uint(score1[b * N2_ + f]) >> 19], 1u);
  }
  __syncthreads();
  suffix_select(hist, wtot, 0u, (u32)K1_, &sh_bin, &sh_next);
  const int b1 = sh_bin;
  const u32 base = sh_next;

  if (b1 >= 0) {
    for (int i = tid; i < NBIN; i += 1024) hist[i] = 0;
    if (tid == 0) sh_bin = -2;
    __syncthreads();
    for (int f = tid; f < N2_; f += 1024) {
      if (keep1[b * N2_ + f]) {
        u32 k = __float_as_uint(score1[b * N2_ + f]);
        if ((int)(k >> 19) == b1) atomicAdd(&hist[(k >> 7) & 0xFFFu], 1u);
      }
    }
    __syncthreads();
    suffix_select(hist, wtot, base, (u32)K1_, &sh_bin, &sh_next);
    if (tid == 0) {
      int b2 = sh_bin;
      sh_T = (b2 >= 0) ? ((((u32)b1) << 19) | (((u32)b2) << 7))
                       : (((u32)b1) << 19);
    }
  } else {
    if (tid == 0) sh_T = 0;
  }
  if (tid == 0) sh_cnt = 0;
  __syncthreads();

  const u32 T = sh_T;
  for (int f = tid; f < N2_; f += 1024) {
    if (keep1[b * N2_ + f]) {
      u32 k = __float_as_uint(score1[b * N2_ + f]);
      if (k >= T) {
        u32 pos = atomicAdd(&sh_cnt, 1u);
        if (pos < CAP) buf[pos] = ((u64)k << 32) | (u32)(~(u32)f);
      }
    }
  }
  __syncthreads();
  u32 m = sh_cnt; if (m > CAP) m = CAP;
  const u32 n = next_pow2_ge(m, 1024u, (u32)CAP);
  for (u32 i = tid; i < n; i += 1024)
    if (i >= m) buf[i] = 0ull;
  bitonic_sort_desc_ws(buf, n, tid);

  if (tid < K1_) {
    u64 e = buf[tid];
    u32 k = (u32)(e >> 32);
    float s; int cls, orig;
    if (k == 0) { s = -1.0f; cls = 0; orig = 0; }
    else {
      s = __uint_as_float(k);
      u32 f = ~(u32)e;
      cls = (int)(f / K1_);
      int slot = (int)(f - (u32)cls * K1_);
      orig = idx1[(b * C_ + cls) * K1_ + slot];
    }
    sel_score[b * K1_ + tid] = s;
    sel_cls[b * K1_ + tid] = cls;
    sel_orig[b * K1_ + tid] = orig;
  }
}

__global__ __launch_bounds__(1024) void k_nms2_out(const float* __restrict__ boxes,
                                                   const float* __restrict__ sel_score,
                                                   const int* __restrict__ sel_cls,
                                                   const int* __restrict__ sel_orig,
                                                   float* __restrict__ out) {
  __shared__ float4 box4[1024];
  __shared__ float area[1024];
  __shared__ u64 mask[SEGROWS * 16];
  __shared__ u64 validw[16], keepw[16];
  __shared__ short ord[K1_];
  __shared__ int lbase[17];
  __shared__ int ordc;

  const int b = blockIdx.x;
  const int tid = threadIdx.x;
  nms_run(sel_score + b * K1_, sel_orig + b * K1_,
          boxes + (size_t)b * N_ * 4, POST_IOU_F,
          box4, area, mask, validw, keepw);
  __syncthreads();

  if (tid == 0) {
    int acc = 0;
    for (int wdx = 0; wdx < 16; ++wdx) {
      lbase[wdx] = acc;
      acc += __popcll(keepw[wdx]);
    }
    lbase[16] = acc;
    ordc = acc;
  }
  __syncthreads();
  if (tid < 16) {
    u64 m = keepw[tid];
    int base = lbase[tid];
    while (m) {
      int bit = __ffsll((long long)m) - 1;
      ord[base++] = (short)((tid << 6) | bit);
      m &= m - 1;
    }
  }
  __syncthreads();

  for (int t = tid; t < K1_ * 6; t += 1024) out[(size_t)b * K1_ * 6 + t] = 0.0f;
  __syncthreads();

  const int cnt = ordc;
  for (int q = tid; q < cnt; q += 1024) {
    int p = ord[q];
    int oi = sel_orig[b * K1_ + p];
    const float4 bp = *(const float4*)(boxes + ((size_t)b * N_ + oi) * 4);
    float* o = out + ((size_t)b * K1_ + q) * 6;
    o[0] = bp.x; o[1] = bp.y; o[2] = bp.z; o[3] = bp.w;
    o[4] = (float)sel_cls[b * K1_ + p];
    o[5] = sel_score[b * K1_ + p];
  }
}

// ---------------------------------------------------------------------------
static inline void m_split(float cf, float* m1, float* m0, bool* strict) {
  u32 b; memcpy(&b, &cf, 4);
  u32 nb = b + 1; float cn; memcpy(&cn, &nb, 4);
  double M = ((double)cf + (double)cn) * 0.5;
  *m1 = (float)M;
  *m0 = (float)(M - (double)*m1);
  *strict = ((b & 1u) == 0u);
}

extern "C" void kernel_launch(void* const* d_in, const int* in_sizes, int n_in,
                              void* d_out, int out_size, void* d_ws, size_t ws_size,
                              hipStream_t stream) {
  const float* cls = (const float*)d_in[0];    // (8,100000,10) f32
  const float* boxes = (const float*)d_in[1];  // (8,100000,4)  f32
  float* out = (float*)d_out;                  // (8,1000,6)    f32

  char* ws = (char*)d_ws;
  float* score1    = (float*)(ws);                     // 80000 f32
  int*   idx1      = (int*)(ws + 320000);              // 80000 i32
  int*   keep1     = (int*)(ws + 640000);              // 80000 i32
  float* sel_score = (float*)(ws + 960000);            // 8000 f32 (fallback)
  int*   sel_cls   = (int*)(ws + 992000);              // 8000 i32 (fallback)
  int*   sel_orig  = (int*)(ws + 1024000);             // 8000 i32 (fallback)
  u32*   hdr       = (u32*)(ws + 1056000);             // 512*84 u32   -> 1228032
  u64*   cand      = (u64*)(ws + 1228032);             // 512*512 u64  -> 3325184
  u64*   mask1     = (u64*)(ws + 3325184);             // 80*8704 u64  -> 8895744
  u64*   mask2     = (u64*)(ws + 3325184);             // aliases mask1 (dead before reuse)
  float4* cor1     = (float4*)(ws + 8895744);          // 80*1024 f4   -> 10206464
  const size_t WS_NEED = 10206464;

  const int do_fast = (ws_size >= WS_NEED) ? 1 : 0;

  float m1a, m0a, m1b, m0b; bool sa, sb;
  m_split(NMS_IOU_F, &m1a, &m0a, &sa);   // 0.4f  -> strict = false
  m_split(POST_IOU_F, &m1b, &m0b, &sb);  // 0.65f -> strict = true

  hipLaunchKernelGGL(k_compact, dim3(CBLK), dim3(256), 0, stream,
                     cls, cand, hdr);
  hipLaunchKernelGGL(k_sel, dim3(B_ * C_), dim3(1024), 0, stream,
                     cls, cand, hdr, score1, idx1, boxes, cor1, do_fast);

  if (do_fast) {
    if (sa)
      hipLaunchKernelGGL(k_nms1f<true>, dim3(B_ * C_), dim3(1024), 0, stream,
                         cor1, score1, m1a, m0a, mask1, keep1);
    else
      hipLaunchKernelGGL(k_nms1f<false>, dim3(B_ * C_), dim3(1024), 0, stream,
                         cor1, score1, m1a, m0a, mask1, keep1);
    if (sb)
      hipLaunchKernelGGL(k_final<true>, dim3(B_), dim3(1024), 0, stream,
                         score1, idx1, keep1, boxes, m1b, m0b, mask2, out);
    else
      hipLaunchKernelGGL(k_final<false>, dim3(B_), dim3(1024), 0, stream,
                         score1, idx1, keep1, boxes, m1b, m0b, mask2, out);
  } else {
    hipLaunchKernelGGL(k_nms1, dim3(B_ * C_), dim3(1024), 0, stream,
                       boxes, score1, idx1, keep1);
    hipLaunchKernelGGL(k_topk2, dim3(B_), dim3(1024), 0, stream,
                       score1, idx1, keep1, sel_score, sel_cls, sel_orig);
    hipLaunchKernelGGL(k_nms2_out, dim3(B_), dim3(1024), 0, stream,
                       boxes, sel_score, sel_cls, sel_orig, out);
  }
}

// Round 8
// 212.325 us; speedup vs baseline: 1.4799x; 1.4799x over previous
//
#include <hip/hip_runtime.h>
#include <stdint.h>
#include <string.h>

typedef unsigned int u32;
typedef unsigned long long u64;

#define B_ 8
#define N_ 100000
#define C_ 10
#define K1_ 1000
#define N2_ (C_ * K1_)
#define NBIN 4096
#define CAP 4096       // fallback / topk2 sort capacity
#define CAP_C 2048     // fast-path candidate capacity per slice
#define SEGROWS 256    // fused-NMS segment rows (fallback path)
#define MIN_CONF_F 0.05f
#define NMS_IOU_F 0.4f
#define POST_IOU_F 0.65f
#define T0_F 0.985f    // conservative fast-path threshold (per-slice count ~1500)

#define TOTAL_F4 (B_ * N_ * C_ / 4)  // 2,000,000 float4s
#define CBLK 512                     // compact blocks
#define LCAP 512                     // per-block candidate capacity (lambda~234, 18 sigma)
#define HDRW 84                      // u32 stride per compact-block header

// split-NMS parameters (R2/R4 best-measured geometry)
#define NTILE 136   // upper-triangular 64x64 tiles of the 1024x1024 pair matrix
#define NB_ 34      // build blocks per slice (4 waves each -> 1 tile per wave)
#define TPB_ 4      // tiles per build block

static __device__ __forceinline__ u32 next_pow2_ge(u32 x, u32 lo, u32 hi) {
  u32 n = lo;
  while (n < x && n < hi) n <<= 1;
  return n;
}

// triangular tile id of (rt, w), w >= rt
#define TILE_ID(rt, w) ((rt) * 16 - (((rt) * ((rt) - 1)) >> 1) + ((w) - (rt)))

// Prep: one thread writes one corner record (bit-identical FP to the
// validated k_nms_prep body).
static __device__ __forceinline__ void prep_write(const float* __restrict__ bb,
                                                  float s, int oi,
                                                  float4* __restrict__ cor,
                                                  int pos) {
  bool v = (s >= MIN_CONF_F);
  float cx = 0.f, cy = 0.f, w = 0.f, h = 0.f;
  if (v) {
    const float4 bp = *(const float4*)(bb + (size_t)oi * 4);
    cx = bp.x; cy = bp.y; w = bp.z; h = bp.w;
  }
  float y1 = cy - h * 0.5f, x1 = cx - w * 0.5f;
  float y2 = cy + h * 0.5f, x2 = cx + w * 0.5f;
  cor[pos] = make_float4(y1, x1, y2, x2);
}

// Exact threshold predicate, all-f32 (double-float). Reproduces
// (double)inter OP M*(double)den where M = m1+m0 (25-bit midpoint, product
// exact in f64): t+e = m1*den exactly (TwoProdFMA), r = fl(e + m0*den) —
// single rounding preserves sign incl. exact ties; d = inter-t is exact in
// the decision region (Sterbenz). _rn intrinsics pin against fp-contract.
template <bool STRICT>
static __device__ __forceinline__ bool iou_pred(float inter, float den,
                                                float m1, float m0) {
  float t = __fmul_rn(m1, den);
  float e = __builtin_fmaf(m1, den, -t);
  float r = __builtin_fmaf(m0, den, e);
  float d = __fsub_rn(inter, t);
  return STRICT ? (d > r) : (d >= r);
}

// One 64x64 mask tile from LDS-resident corners/areas (validated R14 body).
template <bool STRICT>
static __device__ __forceinline__ void build_tile(const float4* __restrict__ box4,
                                                  const float* __restrict__ area,
                                                  int tt, int lane,
                                                  float m1, float m0,
                                                  u64* __restrict__ mg) {
  int rt = 0, bse = 0;
  while (tt >= bse + (16 - rt)) { bse += 16 - rt; ++rt; }
  const int w = rt + (tt - bse);
  const int row = (rt << 6) | lane;

  const float4 ib = box4[row];
  const float ia = area[row];
  const float4* jcol = &box4[w << 6];
  const float* jarea = &area[w << 6];
  u32 mhi = 0, mlo = 0;
#pragma unroll 8
  for (int j = 63; j >= 32; --j) {
    const float4 jb = jcol[j];
    const float ja = jarea[j];
    float ih = fminf(ib.z, jb.z) - fmaxf(ib.x, jb.x); ih = fmaxf(ih, 0.0f);
    float iw_ = fminf(ib.w, jb.w) - fmaxf(ib.y, jb.y); iw_ = fmaxf(iw_, 0.0f);
    float inter = ih * iw_;
    float den = fmaxf((ia + ja) - inter, 1e-8f);
    bool p_ = iou_pred<STRICT>(inter, den, m1, m0);
    mhi = (mhi << 1) | (p_ ? 1u : 0u);
  }
#pragma unroll 8
  for (int j = 31; j >= 0; --j) {
    const float4 jb = jcol[j];
    const float ja = jarea[j];
    float ih = fminf(ib.z, jb.z) - fmaxf(ib.x, jb.x); ih = fmaxf(ih, 0.0f);
    float iw_ = fminf(ib.w, jb.w) - fmaxf(ib.y, jb.y); iw_ = fmaxf(iw_, 0.0f);
    float inter = ih * iw_;
    float den = fmaxf((ia + ja) - inter, 1e-8f);
    bool p_ = iou_pred<STRICT>(inter, den, m1, m0);
    mlo = (mlo << 1) | (p_ ? 1u : 0u);
  }
  u64 m = ((u64)mhi << 32) | (u64)mlo;
  if (w == rt) m &= (lane == 63) ? 0ull : (~0ull << (lane + 1));
  mg[(tt << 6) + lane] = m;  // coalesced 512-B store
}

// ---------------------------------------------------------------------------
// Wave-synchronous bitonic sort (desc) for 1024 threads. Steps with j <= 64
// stay inside a wave-owned 128-element block -> no barrier (wave64 LDS ops
// complete in order). Barrier only around cross steps (j >= 128).
// ---------------------------------------------------------------------------
__device__ __forceinline__ void bitonic_sort_desc_ws(u64* buf, u32 n, int tid) {
  bool prev_cross = true;  // initial fill was block-wide scattered -> barrier
  for (u32 kk = 2; kk <= n; kk <<= 1) {
    for (u32 j = kk >> 1; j > 0; j >>= 1) {
      const bool cross = (j >= 128);
      if (cross || prev_cross) __syncthreads();
      for (u32 t = (u32)tid; t < (n >> 1); t += 1024) {
        u32 i = ((t & ~(j - 1)) << 1) | (t & (j - 1));
        u32 l = i | j;
        u64 a = buf[i], bb = buf[l];
        bool desc = ((i & kk) == 0);
        if (desc ? (a < bb) : (a > bb)) { buf[i] = bb; buf[l] = a; }
      }
      prev_cross = cross;
    }
  }
  __syncthreads();  // publish: readers read outside their wave's block
}

// ---------------------------------------------------------------------------
// Pass 1 (LDS-staged compaction). Validated R4 body.
// ---------------------------------------------------------------------------
__global__ __launch_bounds__(256) void k_compact(const float* __restrict__ cls,
                                                 u64* __restrict__ cand,
                                                 u32* __restrict__ hdr) {
  __shared__ u32 lcnt[B_ * C_];
  __shared__ u32 lpre[B_ * C_ + 1];
  __shared__ u32 ltot;
  __shared__ u32 lovf;
  __shared__ u64 ekey[LCAP];
  __shared__ u32 emeta[LCAP];  // (slice<<16) | local_rank

  const int tid = threadIdx.x;
  const u32 bk = blockIdx.x;
  if (tid < B_ * C_) lcnt[tid] = 0;
  if (tid == 0) { ltot = 0; lovf = 0; }
  __syncthreads();

  const u32 lo = bk * ((TOTAL_F4 + CBLK - 1) / CBLK);
  u32 hi = lo + ((TOTAL_F4 + CBLK - 1) / CBLK);
  if (hi > TOTAL_F4) hi = TOTAL_F4;

  const float4* p4 = (const float4*)cls;
  for (u32 f = lo + tid; f < hi; f += 256) {
    float4 v = p4[f];
    u32 e = f * 4u;
    float vs[4] = {v.x, v.y, v.z, v.w};
#pragma unroll
    for (int j = 0; j < 4; ++j) {
      float s = vs[j];
      if (s >= T0_F) {
        u32 g = e + (u32)j;           // flat index into (B,N,C)
        u32 gi = g / (u32)C_;         // b*N + i
        u32 c = g - gi * (u32)C_;
        u32 bi = gi / (u32)N_;
        u32 i = gi - bi * (u32)N_;
        u32 slice = bi * (u32)C_ + c;
        u32 rank = atomicAdd(&lcnt[slice], 1u);
        u32 pos = atomicAdd(&ltot, 1u);
        if (pos < LCAP) {
          ekey[pos] = ((u64)__float_as_uint(s) << 32) | (u32)(~i);
          emeta[pos] = (slice << 16) | rank;
        } else {
          lovf = 1;
        }
      }
    }
  }
  __syncthreads();

  // exclusive prefix of lcnt -> lpre[0..80] (Hillis-Steele, 7 steps)
  if (tid < B_ * C_) lpre[tid + 1] = lcnt[tid];
  if (tid == 0) lpre[0] = 0;
  __syncthreads();
  for (int off = 1; off < B_ * C_; off <<= 1) {
    u32 v = 0;
    const bool act = (tid >= off && tid <= B_ * C_);
    if (act) v = lpre[tid - off];
    __syncthreads();
    if (act) lpre[tid] += v;
    __syncthreads();
  }

  // scatter into slice-grouped segment
  u32 tot = ltot;
  if (tot > LCAP) tot = LCAP;
  u64* seg = cand + (size_t)bk * LCAP;
  for (u32 p = tid; p < tot; p += 256) {
    u32 mta = emeta[p];
    u32 slice = mta >> 16;
    u32 rank = mta & 0xFFFFu;
    u32 dst = lpre[slice] + rank;
    if (dst < LCAP) seg[dst] = ekey[p];  // garbage on ovf; sel ignores then
  }
  if (tid <= B_ * C_) hdr[bk * HDRW + tid] = lpre[tid];
  if (tid == 0) hdr[bk * HDRW + 81] = lovf;
}

// ---------------------------------------------------------------------------
// Pass 2: gather per-slice candidates, wave-sync bitonic sort, emit top 1000.
// Register-resident header combine (2 barriers). Exact histogram fallback
// inlined (statistically dead); prep fused as epilogue. Validated R6 body.
// ---------------------------------------------------------------------------
__global__ __launch_bounds__(1024) void k_sel(const float* __restrict__ cls,
                                              const u64* __restrict__ cand,
                                              const u32* __restrict__ hdr,
                                              float* __restrict__ score1,
                                              int* __restrict__ idx1,
                                              const float* __restrict__ boxes,
                                              float4* __restrict__ cor1,
                                              int do_prep) {
  const int slice = blockIdx.x;
  const int tid = threadIdx.x;
  const int bd = 1024;
  const int lane = tid & 63, wv = tid >> 6;

  __shared__ u32 hist[NBIN];  // fallback histogram only
  __shared__ u64 buf[CAP];
  __shared__ u32 wsum[8];
  __shared__ int sh_b1;
  __shared__ u32 sh_base, sh_T, sh_cnt, sh_ovf;

  if (tid == 0) sh_ovf = 0;
  __syncthreads();

  u32 mycnt = 0, mystart = 0, incl = 0;
  if (tid < CBLK) {
    const u32* h = hdr + (size_t)tid * HDRW;
    u32 a = h[slice], b2 = h[slice + 1];
    mystart = a;
    mycnt = b2 - a;
    if (h[81]) sh_ovf = 1;
    incl = mycnt;
    for (int off = 1; off < 64; off <<= 1) {
      u32 v = (u32)__shfl_up((int)incl, off, 64);
      if (lane >= off) incl += v;
    }
    if (lane == 63) wsum[wv] = incl;
  }
  __syncthreads();

  u32 wbase = 0, m = 0;
#pragma unroll
  for (int w2 = 0; w2 < 8; ++w2) {
    u32 v = wsum[w2];
    if (w2 < wv) wbase += v;
    m += v;
  }
  const bool fast = (sh_ovf == 0) && m >= (u32)K1_ && m <= (u32)CAP_C;

  if (fast) {
    if (tid < CBLK) {
      u32 base = wbase + incl - mycnt;  // exclusive prefix
      const u64* src = cand + (size_t)tid * LCAP + mystart;
      for (u32 r = 0; r < mycnt; ++r) buf[base + r] = src[r];
    }
    const u32 nn = next_pow2_ge(m, 1024u, (u32)CAP_C);
    for (u32 i2 = (u32)tid; i2 < nn; i2 += bd)
      if (i2 >= m) buf[i2] = 0ull;  // disjoint from gather region: no barrier
    bitonic_sort_desc_ws(buf, nn, tid);

    float os = -1.0f; int ooi = 0;
    if (tid < K1_) {
      u64 e = buf[tid];
      u32 k = (u32)(e >> 32);
      os = __uint_as_float(k);     // fast path: k != 0 always (s >= T0)
      ooi = (int)(~(u32)e);
      score1[slice * K1_ + tid] = os;
      idx1[slice * K1_ + tid] = ooi;
    }
    if (do_prep)
      prep_write(boxes + (size_t)(slice / C_) * N_ * 4, os, ooi, cor1,
                 (slice << 10) + tid);
    return;
  }

  // ---- exact fallback: two-level histogram select over the full column ----
  const int b = slice / C_, c = slice % C_;

  for (int i = tid; i < NBIN; i += bd) hist[i] = 0;
  __syncthreads();
  for (int i = tid; i < N_; i += bd) {
    float s = cls[((size_t)b * N_ + i) * C_ + c];
    if (s >= MIN_CONF_F) atomicAdd(&hist[__float_as_uint(s) >> 19], 1u);
  }
  __syncthreads();
  if (tid == 0) {
    u32 cum = 0; int b1 = -1; u32 base = 0;
    for (int bin = NBIN - 1; bin >= 0; --bin) {
      cum += hist[bin];
      if (cum >= (u32)K1_) { b1 = bin; base = cum - hist[bin]; break; }
    }
    sh_b1 = b1; sh_base = base;
    if (b1 < 0) sh_T = 0;
  }
  __syncthreads();
  const int b1 = sh_b1;

  if (b1 >= 0) {
    const u32 base = sh_base;
    for (int i = tid; i < NBIN; i += bd) hist[i] = 0;
    __syncthreads();
    for (int i = tid; i < N_; i += bd) {
      float s = cls[((size_t)b * N_ + i) * C_ + c];
      if (s >= MIN_CONF_F) {
        u32 k = __float_as_uint(s);
        if ((int)(k >> 19) == b1) atomicAdd(&hist[(k >> 7) & 0xFFFu], 1u);
      }
    }
    __syncthreads();
    if (tid == 0) {
      u32 cum = base;
      u32 T = ((u32)b1) << 19;
      for (int bin = NBIN - 1; bin >= 0; --bin) {
        cum += hist[bin];
        if (cum >= (u32)K1_) { T = (((u32)b1) << 19) | (((u32)bin) << 7); break; }
      }
      sh_T = T;
    }
    __syncthreads();
  }

  if (tid == 0) sh_cnt = 0;
  __syncthreads();
  const u32 T = sh_T;
  for (int i = tid; i < N_; i += bd) {
    float s = cls[((size_t)b * N_ + i) * C_ + c];
    if (s >= MIN_CONF_F) {
      u32 k = __float_as_uint(s);
      if (k >= T) {
        u32 pos = atomicAdd(&sh_cnt, 1u);
        if (pos < CAP) buf[pos] = ((u64)k << 32) | (u32)(~(u32)i);
      }
    }
  }
  __syncthreads();
  u32 mm = sh_cnt; if (mm > CAP) mm = CAP;
  for (int i = tid; i < CAP; i += bd)
    if ((u32)i >= mm) buf[i] = 0ull;
  __syncthreads();

  for (u32 kk = 2; kk <= CAP; kk <<= 1) {
    for (u32 j = kk >> 1; j > 0; j >>= 1) {
      for (u32 i = tid; i < CAP; i += bd) {
        u32 l = i ^ j;
        if (l > i) {
          u64 a = buf[i], bb2 = buf[l];
          bool desc = ((i & kk) == 0);
          if (desc ? (a < bb2) : (a > bb2)) { buf[i] = bb2; buf[l] = a; }
        }
      }
      __syncthreads();
    }
  }

  float os = -1.0f; int ooi = 0;
  if (tid < K1_) {
    u64 e = buf[tid];
    u32 k = (u32)(e >> 32);
    if (k != 0) { os = __uint_as_float(k); ooi = (int)(~(u32)e); }
    score1[slice * K1_ + tid] = os;
    idx1[slice * K1_ + tid] = ooi;
  }
  if (do_prep)
    prep_write(boxes + (size_t)(slice / C_) * N_ * 4, os, ooi, cor1,
               (slice << 10) + tid);
}

// ===========================================================================
// Split NMS: build (parallel across CUs) -> hierarchical scan. R4 verbatim.
// ===========================================================================
template <bool STRICT>
__global__ __launch_bounds__(256) void k_nms_build(const float4* __restrict__ cor,
                                                   float m1, float m0,
                                                   u64* __restrict__ maskg) {
  __shared__ float4 box4[1024];
  __shared__ float area[1024];
  const int blk = blockIdx.x;
  const int slice = blk / NB_;
  const int sub = blk - slice * NB_;
  const int tid = threadIdx.x, wave = tid >> 6, lane = tid & 63;

  for (int p = tid; p < 1024; p += 256) {
    const float4 c = cor[(slice << 10) + p];
    box4[p] = c;
    area[p] = (c.z - c.x) * (c.w - c.y);
  }
  __syncthreads();

  u64* mg = maskg + (size_t)slice * (NTILE * 64);

  for (int k = wave; k < TPB_; k += 4) {
    const int tt = sub * TPB_ + k;
    if (tt >= NTILE) break;
    build_tile<STRICT>(box4, area, tt, lane, m1, m0, mg);
  }
}

// Hierarchical scan core (rolled, O(1) registers). Exact greedy keep set.
__device__ void scan_core(const u64* __restrict__ mg, float s,
                          u64* __restrict__ keepb) {
  const int tid = threadIdx.x, wv = tid >> 6, lane = tid & 63;
  const u64 myvalid = __ballot(s >= MIN_CONF_F);

  u64 ext_partial = 0;

#pragma unroll 1
  for (int g = 0; g < 16; ++g) {
    u64 Tg = 0ull;
    if (g <= wv) Tg = mg[(TILE_ID(g, wv) << 6) + lane];
    const u64 nz = __ballot(Tg != 0ull);  // suppressor rows in this tile
    if (wv == g) {
      u64 ext = ext_partial;
      for (int off = 1; off < 64; off <<= 1) {
        u32 lo = (u32)__shfl_xor((int)(u32)ext, off, 64);
        u32 hi = (u32)__shfl_xor((int)(u32)(ext >> 32), off, 64);
        ext |= ((u64)hi << 32) | lo;
      }
      const u32 tlo = (u32)Tg, thi = (u32)(Tg >> 32);
      u64 rem = myvalid & ~ext;
      u64 cand = rem & nz;
      while (cand) {
        int i = __ffsll((long long)cand) - 1;
        cand &= cand - 1;  // clear bit i
        if ((rem >> i) & 1ull) {
          u32 rlo = __builtin_amdgcn_readlane(tlo, i);
          u32 rhi = __builtin_amdgcn_readlane(thi, i);
          u64 row = ((u64)rhi << 32) | rlo;  // bits only > i (diag-masked)
          rem &= ~row;
          cand &= ~row;
        }
      }
      if (lane == 0) keepb[g] = rem;
    }
    __syncthreads();
    if (wv > g) {
      u64 kg = keepb[g];  // broadcast LDS read
      if ((kg >> lane) & 1ull) ext_partial |= Tg;
    }
  }
}

// scan1 now emits the keep BITMASK (16 u64 per slice) instead of 1000 ints:
// 97% less store traffic, and topk2's keep test becomes an LDS bit probe.
__global__ __launch_bounds__(1024) void k_nms_scan1(const u64* __restrict__ maskg,
                                                    const float* __restrict__ score1,
                                                    u64* __restrict__ keepbg) {
  __shared__ u64 keepb[16];
  const int slice = blockIdx.x;
  const int tid = threadIdx.x;
  float s = (tid < K1_) ? score1[slice * K1_ + tid] : -1.0f;
  scan_core(maskg + (size_t)slice * (NTILE * 64), s, keepb);
  __syncthreads();
  if (tid < 16) keepbg[slice * 16 + tid] = keepb[tid];
}

__global__ __launch_bounds__(1024) void k_nms_scan2(const u64* __restrict__ maskg,
                                                    const float* __restrict__ sel_score,
                                                    const int* __restrict__ sel_cls,
                                                    const int* __restrict__ sel_orig,
                                                    const float* __restrict__ boxes,
                                                    float* __restrict__ out) {
  __shared__ u64 keepb[16];
  __shared__ short ord[K1_];
  __shared__ int lbase[17];
  __shared__ int ordc;
  const int b = blockIdx.x;
  const int tid = threadIdx.x;
  float s = (tid < K1_) ? sel_score[b * K1_ + tid] : -1.0f;
  scan_core(maskg + (size_t)b * (NTILE * 64), s, keepb);
  __syncthreads();

  if (tid == 0) {
    int acc = 0;
    for (int wdx = 0; wdx < 16; ++wdx) {
      lbase[wdx] = acc;
      acc += __popcll(keepb[wdx]);
    }
    lbase[16] = acc;
    ordc = acc;
  }
  __syncthreads();
  if (tid < 16) {
    u64 m = keepb[tid];
    int base = lbase[tid];
    while (m) {
      int bit = __ffsll((long long)m) - 1;
      ord[base++] = (short)((tid << 6) | bit);
      m &= m - 1;
    }
  }
  __syncthreads();

  for (int t = tid; t < K1_ * 6; t += 1024) out[(size_t)b * K1_ * 6 + t] = 0.0f;
  __syncthreads();

  const int cnt = ordc;
  for (int q = tid; q < cnt; q += 1024) {
    int p = ord[q];
    int oi = sel_orig[b * K1_ + p];
    const float4 bp = *(const float4*)(boxes + ((size_t)b * N_ + oi) * 4);
    float* o = out + ((size_t)b * K1_ + q) * 6;
    o[0] = bp.x; o[1] = bp.y; o[2] = bp.z; o[3] = bp.w;
    o[4] = (float)sel_cls[b * K1_ + p];
    o[5] = sel_score[b * K1_ + p];
  }
}

// ---------------------------------------------------------------------------
// Parallel boundary-bin select over a 4096-bin LDS histogram (1024 threads).
// Wave-shuffle suffix scan + 16 wave totals (2 barriers). Validated R6 body.
// ---------------------------------------------------------------------------
__device__ __forceinline__ void suffix_select(const u32* __restrict__ hist,
                                              u32* __restrict__ wtot,  // [16]
                                              u32 base, u32 K,
                                              int* out_bin, u32* out_next) {
  const int t = threadIdx.x;  // 1024
  const int lane = t & 63, wv = t >> 6;
  u32 h0 = hist[4 * t], h1 = hist[4 * t + 1];
  u32 h2 = hist[4 * t + 2], h3 = hist[4 * t + 3];
  const u32 own = h0 + h1 + h2 + h3;
  u32 suf = own;
  for (int off = 1; off < 64; off <<= 1) {
    u32 v = (u32)__shfl_down((int)suf, off, 64);
    if (lane + off < 64) suf += v;
  }
  if (lane == 0) wtot[wv] = suf;
  __syncthreads();
  u32 upw = 0;
#pragma unroll
  for (int w2 = 0; w2 < 16; ++w2) {
    u32 v = wtot[w2];
    if (w2 > wv) upw += v;
  }
  if (t == 0 && base + (suf + upw) < K) { *out_bin = -1; *out_next = base; }
  u32 up = suf - own + upw;  // = aux[t+1]
  u32 s3 = h3 + up;
  u32 s2 = h2 + s3;
  u32 s1 = h1 + s2;
  u32 s0 = h0 + s1;
  u32 c0 = base + s0, c1 = base + s1, c2 = base + s2, c3 = base + s3;
  u32 c4 = base + up;
  if (c0 >= K && c1 < K) { *out_bin = 4 * t;     *out_next = c1; }
  if (c1 >= K && c2 < K) { *out_bin = 4 * t + 1; *out_next = c2; }
  if (c2 >= K && c3 < K) { *out_bin = 4 * t + 2; *out_next = c3; }
  if (c3 >= K && c4 < K) { *out_bin = 4 * t + 3; *out_next = c4; }
  __syncthreads();
}

// ---------------------------------------------------------------------------
// Kernel 3 (fast path): per-batch top-1000 over the C*K1 survivors (stable,
// flat-index tie-break). Keep set comes in as a BITMASK (160 u64 per batch)
// loaded once into LDS — replaces 3 latency-bound global sweeps of the old
// keep1 int array. Prep for pass-2 NMS fused as an epilogue.
// ---------------------------------------------------------------------------
__global__ __launch_bounds__(1024) void k_topk2(const float* __restrict__ score1,
                                                const int* __restrict__ idx1,
                                                const u64* __restrict__ keepbg,
                                                float* __restrict__ sel_score,
                                                int* __restrict__ sel_cls,
                                                int* __restrict__ sel_orig,
                                                const float* __restrict__ boxes,
                                                float4* __restrict__ cor2,
                                                int do_prep) {
  const int b = blockIdx.x;
  const int tid = threadIdx.x;

  __shared__ u32 hist[NBIN];
  __shared__ u32 wtot[16];
  __shared__ u64 buf[CAP];
  __shared__ u64 kmask[C_ * 16];  // batch b's keep bitmask (10 slices x 16)
  __shared__ int sh_bin;
  __shared__ u32 sh_next;
  __shared__ u32 sh_T, sh_cnt;

  if (tid < C_ * 16) kmask[tid] = keepbg[b * (C_ * 16) + tid];
  for (int i = tid; i < NBIN; i += 1024) hist[i] = 0;
  __syncthreads();

#define KEPT(f)                                                       \
  ({ u32 _cls = (u32)(f) / (u32)K1_;                                  \
     u32 _p = (u32)(f) - _cls * (u32)K1_;                             \
     (bool)((kmask[(_cls << 4) + (_p >> 6)] >> (_p & 63)) & 1ull); })

  for (int f = tid; f < N2_; f += 1024) {
    if (KEPT(f))
      atomicAdd(&hist[__float_as_uint(score1[b * N2_ + f]) >> 19], 1u);
  }
  __syncthreads();
  suffix_select(hist, wtot, 0u, (u32)K1_, &sh_bin, &sh_next);
  const int b1 = sh_bin;
  const u32 base = sh_next;

  if (b1 >= 0) {
    for (int i = tid; i < NBIN; i += 1024) hist[i] = 0;
    if (tid == 0) sh_bin = -2;
    __syncthreads();
    for (int f = tid; f < N2_; f += 1024) {
      if (KEPT(f)) {
        u32 k = __float_as_uint(score1[b * N2_ + f]);
        if ((int)(k >> 19) == b1) atomicAdd(&hist[(k >> 7) & 0xFFFu], 1u);
      }
    }
    __syncthreads();
    suffix_select(hist, wtot, base, (u32)K1_, &sh_bin, &sh_next);
    if (tid == 0) {
      int b2 = sh_bin;
      sh_T = (b2 >= 0) ? ((((u32)b1) << 19) | (((u32)b2) << 7))
                       : (((u32)b1) << 19);
    }
  } else {
    if (tid == 0) sh_T = 0;
  }
  if (tid == 0) sh_cnt = 0;
  __syncthreads();

  const u32 T = sh_T;
  for (int f = tid; f < N2_; f += 1024) {
    if (KEPT(f)) {
      u32 k = __float_as_uint(score1[b * N2_ + f]);
      if (k >= T) {
        u32 pos = atomicAdd(&sh_cnt, 1u);
        if (pos < CAP) buf[pos] = ((u64)k << 32) | (u32)(~(u32)f);
      }
    }
  }
#undef KEPT
  __syncthreads();
  u32 m = sh_cnt; if (m > CAP) m = CAP;
  const u32 n = next_pow2_ge(m, 1024u, (u32)CAP);
  for (u32 i = tid; i < n; i += 1024)
    if (i >= m) buf[i] = 0ull;
  bitonic_sort_desc_ws(buf, n, tid);

  float os = -1.0f; int ooi = 0;
  if (tid < K1_) {
    u64 e = buf[tid];
    u32 k = (u32)(e >> 32);
    float s; int cls, orig;
    if (k == 0) { s = -1.0f; cls = 0; orig = 0; }
    else {
      s = __uint_as_float(k);
      u32 f = ~(u32)e;
      cls = (int)(f / K1_);
      int slot = (int)(f - (u32)cls * K1_);
      orig = idx1[(b * C_ + cls) * K1_ + slot];
    }
    sel_score[b * K1_ + tid] = s;
    sel_cls[b * K1_ + tid] = cls;
    sel_orig[b * K1_ + tid] = orig;
    os = s; ooi = orig;
  }
  if (do_prep)
    prep_write(boxes + (size_t)b * N_ * 4, os, ooi, cor2, (b << 10) + tid);
}

// ===========================================================================
// Fallback path (ws too small) — validated R8 fused NMS + int-keep1 topk2.
// ===========================================================================
__device__ __forceinline__ void nms_run(const float* __restrict__ scores,
                                        const int* __restrict__ origs,
                                        const float* __restrict__ boxesB,
                                        float thr,
                                        float4* box4, float* area,
                                        u64* mask, u64* validw, u64* keepw) {
  const int tid = threadIdx.x;
  const int wave = tid >> 6, lane = tid & 63;

  {
    const int p = tid;
    float s = (p < K1_) ? scores[p] : -1.0f;
    bool v = (s >= MIN_CONF_F);
    float cx = 0.f, cy = 0.f, w = 0.f, h = 0.f;
    if (v) {
      const float4 bp = *(const float4*)(boxesB + (size_t)origs[p] * 4);
      cx = bp.x; cy = bp.y; w = bp.z; h = bp.w;
    }
    float y1 = cy - h * 0.5f, x1 = cx - w * 0.5f;
    float y2 = cy + h * 0.5f, x2 = cx + w * 0.5f;
    box4[p] = make_float4(y1, x1, y2, x2);
    area[p] = (y2 - y1) * (x2 - x1);
    u64 mb = __ballot(v);
    if (lane == 0) validw[wave] = mb;
  }
  __syncthreads();

  const float cf = thr;
  const float cnext = __uint_as_float(__float_as_uint(cf) + 1u);
  const double M = ((double)cf + (double)cnext) * 0.5;
  const bool strict = ((__float_as_uint(cf) & 1u) == 0u);

  const int ss = wave & 3, qq = wave >> 2;
  int col;
  if (qq == 0) col = ss;
  else if (qq == 1) col = 7 - ss;
  else if (qq == 2) col = 8 + ss;
  else col = 15 - ss;

  u64 vw = validw[tid & 15];
  u64 supp = 0;

  for (int seg = 0; seg < 4; ++seg) {
    const int ibase = seg * SEGROWS;
    const int lim = (K1_ - ibase < SEGROWS) ? (K1_ - ibase) : SEGROWS;
    const int rtg0 = ibase >> 6;
    int ntile = col - rtg0 + 1;
    if (ntile < 0) ntile = 0;
    if (ntile > 4) ntile = 4;

    if (ntile > 0) {
      float4 ib[4];
      float ia[4];
#pragma unroll
      for (int r = 0; r < 4; ++r) {
        if (r < ntile) {
          const int i = ibase + (r << 6) + lane;
          ib[r] = box4[i];
          ia[r] = area[i];
        }
      }
      u32 mhi[4] = {0, 0, 0, 0}, mlo[4] = {0, 0, 0, 0};
      const float4* jcol = &box4[col << 6];

      for (int j = 63; j >= 32; --j) {
        const float4 jb = jcol[j];
        const float ja = (jb.z - jb.x) * (jb.w - jb.y);
#pragma unroll
        for (int r = 0; r < 4; ++r) {
          if (r < ntile) {
            float ih = fminf(ib[r].z, jb.z) - fmaxf(ib[r].x, jb.x);
            ih = fmaxf(ih, 0.0f);
            float iw_ = fminf(ib[r].w, jb.w) - fmaxf(ib[r].y, jb.y);
            iw_ = fmaxf(iw_, 0.0f);
            float inter = ih * iw_;
            float den = fmaxf((ia[r] + ja) - inter, 1e-8f);
            bool p_ = strict ? ((double)inter > M * (double)den)
                             : ((double)inter >= M * (double)den);
            mhi[r] = (mhi[r] << 1) | (p_ ? 1u : 0u);
          }
        }
      }
      for (int j = 31; j >= 0; --j) {
        const float4 jb = jcol[j];
        const float ja = (jb.z - jb.x) * (jb.w - jb.y);
#pragma unroll
        for (int r = 0; r < 4; ++r) {
          if (r < ntile) {
            float ih = fminf(ib[r].z, jb.z) - fmaxf(ib[r].x, jb.x);
            ih = fmaxf(ih, 0.0f);
            float iw_ = fminf(ib[r].w, jb.w) - fmaxf(ib[r].y, jb.y);
            iw_ = fmaxf(iw_, 0.0f);
            float inter = ih * iw_;
            float den = fmaxf((ia[r] + ja) - inter, 1e-8f);
            bool p_ = strict ? ((double)inter > M * (double)den)
                             : ((double)inter >= M * (double)den);
            mlo[r] = (mlo[r] << 1) | (p_ ? 1u : 0u);
          }
        }
      }
#pragma unroll
      for (int r = 0; r < 4; ++r) {
        if (r < ntile) {
          u64 m = ((u64)mhi[r] << 32) | (u64)mlo[r];
          if (rtg0 + r == col)
            m &= (lane == 63) ? 0ull : (~0ull << (lane + 1));
          const int il = (r << 6) | lane;
          mask[il * 16 + (col ^ (il & 15))] = m;
        }
      }
    }
    __syncthreads();

    if (tid < 64) {
      const int l = tid & 15;
      u64 r0 = 0, r1 = 0, r2 = 0, r3 = 0;
      if (l >= ((ibase + 0) >> 6)) r0 = mask[0 * 16 + (l ^ 0)];
      if (l >= ((ibase + 1) >> 6)) r1 = mask[1 * 16 + (l ^ 1)];
      if (l >= ((ibase + 2) >> 6)) r2 = mask[2 * 16 + (l ^ 2)];
      if (l >= ((ibase + 3) >> 6)) r3 = mask[3 * 16 + (l ^ 3)];
      for (int il = 0; il < lim; il += 4) {
        const int i0 = ibase + il;
        const int n0 = (il + 4 < lim) ? il + 4 : il;
        const int n1 = (il + 5 < lim) ? il + 5 : il;
        const int n2 = (il + 6 < lim) ? il + 6 : il;
        const int n3 = (il + 7 < lim) ? il + 7 : il;
        u64 m0 = r0, m1 = r1, m2 = r2, m3 = r3;
        r0 = (l >= ((ibase + n0) >> 6)) ? mask[n0 * 16 + (l ^ (n0 & 15))] : 0ull;
        r1 = (l >= ((ibase + n1) >> 6)) ? mask[n1 * 16 + (l ^ (n1 & 15))] : 0ull;
        r2 = (l >= ((ibase + n2) >> 6)) ? mask[n2 * 16 + (l ^ (n2 & 15))] : 0ull;
        r3 = (l >= ((ibase + n3) >> 6)) ? mask[n3 * 16 + (l ^ (n3 & 15))] : 0ull;
        bool a;
        a = (tid == (i0 >> 6)) && (((vw & ~supp) >> (i0 & 63)) & 1ull);
        if (__any(a)) supp |= m0;
        a = (tid == ((i0 + 1) >> 6)) && (((vw & ~supp) >> ((i0 + 1) & 63)) & 1ull);
        if (__any(a)) supp |= m1;
        a = (tid == ((i0 + 2) >> 6)) && (((vw & ~supp) >> ((i0 + 2) & 63)) & 1ull);
        if (__any(a)) supp |= m2;
        a = (tid == ((i0 + 3) >> 6)) && (((vw & ~supp) >> ((i0 + 3) & 63)) & 1ull);
        if (__any(a)) supp |= m3;
      }
    }
    __syncthreads();
  }

  if (tid < 16) keepw[tid] = vw & ~supp;
}

__global__ __launch_bounds__(1024) void k_nms1(const float* __restrict__ boxes,
                                               const float* __restrict__ score1,
                                               const int* __restrict__ idx1,
                                               int* __restrict__ keep1) {
  __shared__ float4 box4[1024];
  __shared__ float area[1024];
  __shared__ u64 mask[SEGROWS * 16];
  __shared__ u64 validw[16], keepw[16];

  const int slice = blockIdx.x;
  const int b = slice / C_;
  nms_run(score1 + slice * K1_, idx1 + slice * K1_,
          boxes + (size_t)b * N_ * 4, NMS_IOU_F,
          box4, area, mask, validw, keepw);
  __syncthreads();

  const int p = threadIdx.x;
  if (p < K1_)
    keep1[slice * K1_ + p] = (int)((keepw[p >> 6] >> (p & 63)) & 1ull);
}

__global__ __launch_bounds__(1024) void k_topk2_fb(const float* __restrict__ score1,
                                                   const int* __restrict__ idx1,
                                                   const int* __restrict__ keep1,
                                                   float* __restrict__ sel_score,
                                                   int* __restrict__ sel_cls,
                                                   int* __restrict__ sel_orig) {
  const int b = blockIdx.x;
  const int tid = threadIdx.x;

  __shared__ u32 hist[NBIN];
  __shared__ u32 wtot[16];
  __shared__ u64 buf[CAP];
  __shared__ int sh_bin;
  __shared__ u32 sh_next;
  __shared__ u32 sh_T, sh_cnt;

  for (int i = tid; i < NBIN; i += 1024) hist[i] = 0;
  __syncthreads();
  for (int f = tid; f < N2_; f += 1024) {
    if (keep1[b * N2_ + f])
      atomicAdd(&hist[__float_as_uint(score1[b * N2_ + f]) >> 19], 1u);
  }
  __syncthreads();
  suffix_select(hist, wtot, 0u, (u32)K1_, &sh_bin, &sh_next);
  const int b1 = sh_bin;
  const u32 base = sh_next;

  if (b1 >= 0) {
    for (int i = tid; i < NBIN; i += 1024) hist[i] = 0;
    if (tid == 0) sh_bin = -2;
    __syncthreads();
    for (int f = tid; f < N2_; f += 1024) {
      if (keep1[b * N2_ + f]) {
        u32 k = __float_as_uint(score1[b * N2_ + f]);
        if ((int)(k >> 19) == b1) atomicAdd(&hist[(k >> 7) & 0xFFFu], 1u);
      }
    }
    __syncthreads();
    suffix_select(hist, wtot, base, (u32)K1_, &sh_bin, &sh_next);
    if (tid == 0) {
      int b2 = sh_bin;
      sh_T = (b2 >= 0) ? ((((u32)b1) << 19) | (((u32)b2) << 7))
                       : (((u32)b1) << 19);
    }
  } else {
    if (tid == 0) sh_T = 0;
  }
  if (tid == 0) sh_cnt = 0;
  __syncthreads();

  const u32 T = sh_T;
  for (int f = tid; f < N2_; f += 1024) {
    if (keep1[b * N2_ + f]) {
      u32 k = __float_as_uint(score1[b * N2_ + f]);
      if (k >= T) {
        u32 pos = atomicAdd(&sh_cnt, 1u);
        if (pos < CAP) buf[pos] = ((u64)k << 32) | (u32)(~(u32)f);
      }
    }
  }
  __syncthreads();
  u32 m = sh_cnt; if (m > CAP) m = CAP;
  const u32 n = next_pow2_ge(m, 1024u, (u32)CAP);
  for (u32 i = tid; i < n; i += 1024)
    if (i >= m) buf[i] = 0ull;
  bitonic_sort_desc_ws(buf, n, tid);

  if (tid < K1_) {
    u64 e = buf[tid];
    u32 k = (u32)(e >> 32);
    float s; int cls, orig;
    if (k == 0) { s = -1.0f; cls = 0; orig = 0; }
    else {
      s = __uint_as_float(k);
      u32 f = ~(u32)e;
      cls = (int)(f / K1_);
      int slot = (int)(f - (u32)cls * K1_);
      orig = idx1[(b * C_ + cls) * K1_ + slot];
    }
    sel_score[b * K1_ + tid] = s;
    sel_cls[b * K1_ + tid] = cls;
    sel_orig[b * K1_ + tid] = orig;
  }
}

__global__ __launch_bounds__(1024) void k_nms2_out(const float* __restrict__ boxes,
                                                   const float* __restrict__ sel_score,
                                                   const int* __restrict__ sel_cls,
                                                   const int* __restrict__ sel_orig,
                                                   float* __restrict__ out) {
  __shared__ float4 box4[1024];
  __shared__ float area[1024];
  __shared__ u64 mask[SEGROWS * 16];
  __shared__ u64 validw[16], keepw[16];
  __shared__ short ord[K1_];
  __shared__ int lbase[17];
  __shared__ int ordc;

  const int b = blockIdx.x;
  const int tid = threadIdx.x;
  nms_run(sel_score + b * K1_, sel_orig + b * K1_,
          boxes + (size_t)b * N_ * 4, POST_IOU_F,
          box4, area, mask, validw, keepw);
  __syncthreads();

  if (tid == 0) {
    int acc = 0;
    for (int wdx = 0; wdx < 16; ++wdx) {
      lbase[wdx] = acc;
      acc += __popcll(keepw[wdx]);
    }
    lbase[16] = acc;
    ordc = acc;
  }
  __syncthreads();
  if (tid < 16) {
    u64 m = keepw[tid];
    int base = lbase[tid];
    while (m) {
      int bit = __ffsll((long long)m) - 1;
      ord[base++] = (short)((tid << 6) | bit);
      m &= m - 1;
    }
  }
  __syncthreads();

  for (int t = tid; t < K1_ * 6; t += 1024) out[(size_t)b * K1_ * 6 + t] = 0.0f;
  __syncthreads();

  const int cnt = ordc;
  for (int q = tid; q < cnt; q += 1024) {
    int p = ord[q];
    int oi = sel_orig[b * K1_ + p];
    const float4 bp = *(const float4*)(boxes + ((size_t)b * N_ + oi) * 4);
    float* o = out + ((size_t)b * K1_ + q) * 6;
    o[0] = bp.x; o[1] = bp.y; o[2] = bp.z; o[3] = bp.w;
    o[4] = (float)sel_cls[b * K1_ + p];
    o[5] = sel_score[b * K1_ + p];
  }
}

// ---------------------------------------------------------------------------
static inline void m_split(float cf, float* m1, float* m0, bool* strict) {
  u32 b; memcpy(&b, &cf, 4);
  u32 nb = b + 1; float cn; memcpy(&cn, &nb, 4);
  double M = ((double)cf + (double)cn) * 0.5;
  *m1 = (float)M;
  *m0 = (float)(M - (double)*m1);
  *strict = ((b & 1u) == 0u);
}

extern "C" void kernel_launch(void* const* d_in, const int* in_sizes, int n_in,
                              void* d_out, int out_size, void* d_ws, size_t ws_size,
                              hipStream_t stream) {
  const float* cls = (const float*)d_in[0];    // (8,100000,10) f32
  const float* boxes = (const float*)d_in[1];  // (8,100000,4)  f32
  float* out = (float*)d_out;                  // (8,1000,6)    f32

  char* ws = (char*)d_ws;
  float* score1    = (float*)(ws);                     // 80000 f32
  int*   idx1      = (int*)(ws + 320000);              // 80000 i32
  int*   keep1     = (int*)(ws + 640000);              // fallback: 80000 i32
  u64*   keepbg    = (u64*)(ws + 640000);              // fast: 80*16 u64 (same region)
  float* sel_score = (float*)(ws + 960000);            // 8000 f32
  int*   sel_cls   = (int*)(ws + 992000);              // 8000 i32
  int*   sel_orig  = (int*)(ws + 1024000);             // 8000 i32
  u32*   hdr       = (u32*)(ws + 1056000);             // 512*84 u32   -> 1228032
  u64*   cand      = (u64*)(ws + 1228032);             // 512*512 u64  -> 3325184
  u64*   mask1     = (u64*)(ws + 3325184);             // 80*8704 u64  -> 8895744
  u64*   mask2     = (u64*)(ws + 3325184);             // aliases mask1 (dead before reuse)
  float4* cor1     = (float4*)(ws + 8895744);          // 80*1024 f4   -> 10206464
  float4* cor2     = (float4*)(ws + 8895744);          // aliases cor1 (dead before reuse)
  const size_t WS_NEED = 10206464;

  const int do_fast = (ws_size >= WS_NEED) ? 1 : 0;

  float m1a, m0a, m1b, m0b; bool sa, sb;
  m_split(NMS_IOU_F, &m1a, &m0a, &sa);   // 0.4f  -> strict = false
  m_split(POST_IOU_F, &m1b, &m0b, &sb);  // 0.65f -> strict = true

  hipLaunchKernelGGL(k_compact, dim3(CBLK), dim3(256), 0, stream,
                     cls, cand, hdr);
  hipLaunchKernelGGL(k_sel, dim3(B_ * C_), dim3(1024), 0, stream,
                     cls, cand, hdr, score1, idx1, boxes, cor1, do_fast);

  if (do_fast) {
    if (sa)
      hipLaunchKernelGGL(k_nms_build<true>, dim3(B_ * C_ * NB_), dim3(256), 0,
                         stream, cor1, m1a, m0a, mask1);
    else
      hipLaunchKernelGGL(k_nms_build<false>, dim3(B_ * C_ * NB_), dim3(256), 0,
                         stream, cor1, m1a, m0a, mask1);
    hipLaunchKernelGGL(k_nms_scan1, dim3(B_ * C_), dim3(1024), 0, stream,
                       mask1, score1, keepbg);
    hipLaunchKernelGGL(k_topk2, dim3(B_), dim3(1024), 0, stream,
                       score1, idx1, keepbg, sel_score, sel_cls, sel_orig,
                       boxes, cor2, 1);
    if (sb)
      hipLaunchKernelGGL(k_nms_build<true>, dim3(B_ * NB_), dim3(256), 0,
                         stream, cor2, m1b, m0b, mask2);
    else
      hipLaunchKernelGGL(k_nms_build<false>, dim3(B_ * NB_), dim3(256), 0,
                         stream, cor2, m1b, m0b, mask2);
    hipLaunchKernelGGL(k_nms_scan2, dim3(B_), dim3(1024), 0, stream,
                       mask2, sel_score, sel_cls, sel_orig, boxes, out);
  } else {
    hipLaunchKernelGGL(k_nms1, dim3(B_ * C_), dim3(1024), 0, stream,
                       boxes, score1, idx1, keep1);
    hipLaunchKernelGGL(k_topk2_fb, dim3(B_), dim3(1024), 0, stream,
                       score1, idx1, keep1, sel_score, sel_cls, sel_orig);
    hipLaunchKernelGGL(k_nms2_out, dim3(B_), dim3(1024), 0, stream,
                       boxes, sel_score, sel_cls, sel_orig, out);
  }
}

// Round 9
// 210.541 us; speedup vs baseline: 1.4924x; 1.0085x over previous
//
#include <hip/hip_runtime.h>
#include <stdint.h>
#include <string.h>

typedef unsigned int u32;
typedef unsigned long long u64;

#define B_ 8
#define N_ 100000
#define C_ 10
#define K1_ 1000
#define N2_ (C_ * K1_)
#define NBIN 4096
#define CAP 4096       // fallback / topk2 sort capacity
#define CAP_C 2048     // fast-path candidate capacity per slice
#define SEGROWS 256    // fused-NMS segment rows (fallback path)
#define MIN_CONF_F 0.05f
#define NMS_IOU_F 0.4f
#define POST_IOU_F 0.65f
#define T0_F 0.985f    // conservative fast-path threshold (per-slice count ~1500)
#define T0_BITS 0x3F7C28F6u   // float bits of 0.985f
#define BASE7 (T0_BITS >> 7)  // fine-histogram base (candidates span <4096 bins)

#define TOTAL_F4 (B_ * N_ * C_ / 4)  // 2,000,000 float4s
#define CBLK 512                     // compact blocks
#define LCAP 512                     // per-block candidate capacity (lambda~234, 18 sigma)
#define HDRW 84                      // u32 stride per compact-block header

// split-NMS parameters (R2/R4 best-measured geometry)
#define NTILE 136   // upper-triangular 64x64 tiles of the 1024x1024 pair matrix
#define NB_ 34      // build blocks per slice (4 waves each -> 1 tile per wave)
#define TPB_ 4      // tiles per build block

static __device__ __forceinline__ u32 next_pow2_ge(u32 x, u32 lo, u32 hi) {
  u32 n = lo;
  while (n < x && n < hi) n <<= 1;
  return n;
}

// triangular tile id of (rt, w), w >= rt
#define TILE_ID(rt, w) ((rt) * 16 - (((rt) * ((rt) - 1)) >> 1) + ((w) - (rt)))

// Prep: one thread writes one corner record (bit-identical FP to the
// validated k_nms_prep body).
static __device__ __forceinline__ void prep_write(const float* __restrict__ bb,
                                                  float s, int oi,
                                                  float4* __restrict__ cor,
                                                  int pos) {
  bool v = (s >= MIN_CONF_F);
  float cx = 0.f, cy = 0.f, w = 0.f, h = 0.f;
  if (v) {
    const float4 bp = *(const float4*)(bb + (size_t)oi * 4);
    cx = bp.x; cy = bp.y; w = bp.z; h = bp.w;
  }
  float y1 = cy - h * 0.5f, x1 = cx - w * 0.5f;
  float y2 = cy + h * 0.5f, x2 = cx + w * 0.5f;
  cor[pos] = make_float4(y1, x1, y2, x2);
}

// Exact threshold predicate, all-f32 (double-float). Reproduces
// (double)inter OP M*(double)den where M = m1+m0 (25-bit midpoint, product
// exact in f64): t+e = m1*den exactly (TwoProdFMA), r = fl(e + m0*den) —
// single rounding preserves sign incl. exact ties; d = inter-t is exact in
// the decision region (Sterbenz). _rn intrinsics pin against fp-contract.
template <bool STRICT>
static __device__ __forceinline__ bool iou_pred(float inter, float den,
                                                float m1, float m0) {
  float t = __fmul_rn(m1, den);
  float e = __builtin_fmaf(m1, den, -t);
  float r = __builtin_fmaf(m0, den, e);
  float d = __fsub_rn(inter, t);
  return STRICT ? (d > r) : (d >= r);
}

// One 64x64 mask tile from LDS-resident corners/areas (validated R14 body).
template <bool STRICT>
static __device__ __forceinline__ void build_tile(const float4* __restrict__ box4,
                                                  const float* __restrict__ area,
                                                  int tt, int lane,
                                                  float m1, float m0,
                                                  u64* __restrict__ mg) {
  int rt = 0, bse = 0;
  while (tt >= bse + (16 - rt)) { bse += 16 - rt; ++rt; }
  const int w = rt + (tt - bse);
  const int row = (rt << 6) | lane;

  const float4 ib = box4[row];
  const float ia = area[row];
  const float4* jcol = &box4[w << 6];
  const float* jarea = &area[w << 6];
  u32 mhi = 0, mlo = 0;
#pragma unroll 8
  for (int j = 63; j >= 32; --j) {
    const float4 jb = jcol[j];
    const float ja = jarea[j];
    float ih = fminf(ib.z, jb.z) - fmaxf(ib.x, jb.x); ih = fmaxf(ih, 0.0f);
    float iw_ = fminf(ib.w, jb.w) - fmaxf(ib.y, jb.y); iw_ = fmaxf(iw_, 0.0f);
    float inter = ih * iw_;
    float den = fmaxf((ia + ja) - inter, 1e-8f);
    bool p_ = iou_pred<STRICT>(inter, den, m1, m0);
    mhi = (mhi << 1) | (p_ ? 1u : 0u);
  }
#pragma unroll 8
  for (int j = 31; j >= 0; --j) {
    const float4 jb = jcol[j];
    const float ja = jarea[j];
    float ih = fminf(ib.z, jb.z) - fmaxf(ib.x, jb.x); ih = fmaxf(ih, 0.0f);
    float iw_ = fminf(ib.w, jb.w) - fmaxf(ib.y, jb.y); iw_ = fmaxf(iw_, 0.0f);
    float inter = ih * iw_;
    float den = fmaxf((ia + ja) - inter, 1e-8f);
    bool p_ = iou_pred<STRICT>(inter, den, m1, m0);
    mlo = (mlo << 1) | (p_ ? 1u : 0u);
  }
  u64 m = ((u64)mhi << 32) | (u64)mlo;
  if (w == rt) m &= (lane == 63) ? 0ull : (~0ull << (lane + 1));
  mg[(tt << 6) + lane] = m;  // coalesced 512-B store
}

// ---------------------------------------------------------------------------
// Wave-synchronous bitonic sort (desc) for 1024 threads. Steps with j <= 64
// stay inside a wave-owned 128-element block -> no barrier (wave64 LDS ops
// complete in order). Barrier only around cross steps (j >= 128).
// ---------------------------------------------------------------------------
__device__ __forceinline__ void bitonic_sort_desc_ws(u64* buf, u32 n, int tid) {
  bool prev_cross = true;  // initial fill was block-wide scattered -> barrier
  for (u32 kk = 2; kk <= n; kk <<= 1) {
    for (u32 j = kk >> 1; j > 0; j >>= 1) {
      const bool cross = (j >= 128);
      if (cross || prev_cross) __syncthreads();
      for (u32 t = (u32)tid; t < (n >> 1); t += 1024) {
        u32 i = ((t & ~(j - 1)) << 1) | (t & (j - 1));
        u32 l = i | j;
        u64 a = buf[i], bb = buf[l];
        bool desc = ((i & kk) == 0);
        if (desc ? (a < bb) : (a > bb)) { buf[i] = bb; buf[l] = a; }
      }
      prev_cross = cross;
    }
  }
  __syncthreads();  // publish: readers read outside their wave's block
}

// ---------------------------------------------------------------------------
// Pass 1 (LDS-staged compaction). Validated R4 body.
// ---------------------------------------------------------------------------
__global__ __launch_bounds__(256) void k_compact(const float* __restrict__ cls,
                                                 u64* __restrict__ cand,
                                                 u32* __restrict__ hdr) {
  __shared__ u32 lcnt[B_ * C_];
  __shared__ u32 lpre[B_ * C_ + 1];
  __shared__ u32 ltot;
  __shared__ u32 lovf;
  __shared__ u64 ekey[LCAP];
  __shared__ u32 emeta[LCAP];  // (slice<<16) | local_rank

  const int tid = threadIdx.x;
  const u32 bk = blockIdx.x;
  if (tid < B_ * C_) lcnt[tid] = 0;
  if (tid == 0) { ltot = 0; lovf = 0; }
  __syncthreads();

  const u32 lo = bk * ((TOTAL_F4 + CBLK - 1) / CBLK);
  u32 hi = lo + ((TOTAL_F4 + CBLK - 1) / CBLK);
  if (hi > TOTAL_F4) hi = TOTAL_F4;

  const float4* p4 = (const float4*)cls;
  for (u32 f = lo + tid; f < hi; f += 256) {
    float4 v = p4[f];
    u32 e = f * 4u;
    float vs[4] = {v.x, v.y, v.z, v.w};
#pragma unroll
    for (int j = 0; j < 4; ++j) {
      float s = vs[j];
      if (s >= T0_F) {
        u32 g = e + (u32)j;           // flat index into (B,N,C)
        u32 gi = g / (u32)C_;         // b*N + i
        u32 c = g - gi * (u32)C_;
        u32 bi = gi / (u32)N_;
        u32 i = gi - bi * (u32)N_;
        u32 slice = bi * (u32)C_ + c;
        u32 rank = atomicAdd(&lcnt[slice], 1u);
        u32 pos = atomicAdd(&ltot, 1u);
        if (pos < LCAP) {
          ekey[pos] = ((u64)__float_as_uint(s) << 32) | (u32)(~i);
          emeta[pos] = (slice << 16) | rank;
        } else {
          lovf = 1;
        }
      }
    }
  }
  __syncthreads();

  // exclusive prefix of lcnt -> lpre[0..80] (Hillis-Steele, 7 steps)
  if (tid < B_ * C_) lpre[tid + 1] = lcnt[tid];
  if (tid == 0) lpre[0] = 0;
  __syncthreads();
  for (int off = 1; off < B_ * C_; off <<= 1) {
    u32 v = 0;
    const bool act = (tid >= off && tid <= B_ * C_);
    if (act) v = lpre[tid - off];
    __syncthreads();
    if (act) lpre[tid] += v;
    __syncthreads();
  }

  // scatter into slice-grouped segment
  u32 tot = ltot;
  if (tot > LCAP) tot = LCAP;
  u64* seg = cand + (size_t)bk * LCAP;
  for (u32 p = tid; p < tot; p += 256) {
    u32 mta = emeta[p];
    u32 slice = mta >> 16;
    u32 rank = mta & 0xFFFFu;
    u32 dst = lpre[slice] + rank;
    if (dst < LCAP) seg[dst] = ekey[p];  // garbage on ovf; sel ignores then
  }
  if (tid <= B_ * C_) hdr[bk * HDRW + tid] = lpre[tid];
  if (tid == 0) hdr[bk * HDRW + 81] = lovf;
}

// ---------------------------------------------------------------------------
// Parallel boundary-bin select over a 4096-bin LDS histogram (1024 threads).
// Wave-shuffle suffix scan + 16 wave totals (2 barriers). Validated R6 body.
// ---------------------------------------------------------------------------
__device__ __forceinline__ void suffix_select(const u32* __restrict__ hist,
                                              u32* __restrict__ wtot,  // [16]
                                              u32 base, u32 K,
                                              int* out_bin, u32* out_next) {
  const int t = threadIdx.x;  // 1024
  const int lane = t & 63, wv = t >> 6;
  u32 h0 = hist[4 * t], h1 = hist[4 * t + 1];
  u32 h2 = hist[4 * t + 2], h3 = hist[4 * t + 3];
  const u32 own = h0 + h1 + h2 + h3;
  u32 suf = own;
  for (int off = 1; off < 64; off <<= 1) {
    u32 v = (u32)__shfl_down((int)suf, off, 64);
    if (lane + off < 64) suf += v;
  }
  if (lane == 0) wtot[wv] = suf;
  __syncthreads();
  u32 upw = 0;
#pragma unroll
  for (int w2 = 0; w2 < 16; ++w2) {
    u32 v = wtot[w2];
    if (w2 > wv) upw += v;
  }
  if (t == 0 && base + (suf + upw) < K) { *out_bin = -1; *out_next = base; }
  u32 up = suf - own + upw;  // = aux[t+1]
  u32 s3 = h3 + up;
  u32 s2 = h2 + s3;
  u32 s1 = h1 + s2;
  u32 s0 = h0 + s1;
  u32 c0 = base + s0, c1 = base + s1, c2 = base + s2, c3 = base + s3;
  u32 c4 = base + up;
  if (c0 >= K && c1 < K) { *out_bin = 4 * t;     *out_next = c1; }
  if (c1 >= K && c2 < K) { *out_bin = 4 * t + 1; *out_next = c2; }
  if (c2 >= K && c3 < K) { *out_bin = 4 * t + 2; *out_next = c3; }
  if (c3 >= K && c4 < K) { *out_bin = 4 * t + 3; *out_next = c4; }
  __syncthreads();
}

// ---------------------------------------------------------------------------
// Pass 2: gather per-slice candidates, select top-1000 superset via a fine
// 7-bit-shifted histogram (candidates span <4096 bins since score >= T0),
// compact to ~1000 survivors, wave-sync bitonic sort n=1024 (was 2048).
// Ties overflow (>1024 survivors) falls back to sorting the full set — the
// untouched buf[0..m) region — exactly as R8. Exact histogram fallback
// inlined (statistically dead); prep fused as epilogue.
// ---------------------------------------------------------------------------
__global__ __launch_bounds__(1024) void k_sel(const float* __restrict__ cls,
                                              const u64* __restrict__ cand,
                                              const u32* __restrict__ hdr,
                                              float* __restrict__ score1,
                                              int* __restrict__ idx1,
                                              const float* __restrict__ boxes,
                                              float4* __restrict__ cor1,
                                              int do_prep) {
  const int slice = blockIdx.x;
  const int tid = threadIdx.x;
  const int bd = 1024;
  const int lane = tid & 63, wv = tid >> 6;

  __shared__ u32 hist[NBIN];
  __shared__ u64 buf[CAP];
  __shared__ u32 wsum[16];   // [0..7] header wave sums; reused by suffix_select
  __shared__ int sh_b1;
  __shared__ u32 sh_base, sh_T, sh_cnt, sh_ovf;

  if (tid == 0) sh_ovf = 0;
  for (int i = tid; i < NBIN; i += bd) hist[i] = 0;  // published by next barrier

  u32 mycnt = 0, mystart = 0, incl = 0;
  if (tid < CBLK) {
    const u32* h = hdr + (size_t)tid * HDRW;
    u32 a = h[slice], b2 = h[slice + 1];
    mystart = a;
    mycnt = b2 - a;
    if (h[81]) sh_ovf = 1;
    incl = mycnt;
    for (int off = 1; off < 64; off <<= 1) {
      u32 v = (u32)__shfl_up((int)incl, off, 64);
      if (lane >= off) incl += v;
    }
    if (lane == 63) wsum[wv] = incl;
  }
  __syncthreads();

  u32 wbase = 0, m = 0;
#pragma unroll
  for (int w2 = 0; w2 < 8; ++w2) {
    u32 v = wsum[w2];
    if (w2 < wv) wbase += v;
    m += v;
  }
  const bool fast = (sh_ovf == 0) && m >= (u32)K1_ && m <= (u32)CAP_C;

  if (fast) {
    // gather + fine histogram: bin = (k>>7) - BASE7, in [0, ~1968)
    if (tid < CBLK) {
      u32 base = wbase + incl - mycnt;  // exclusive prefix
      const u64* src = cand + (size_t)tid * LCAP + mystart;
      for (u32 r = 0; r < mycnt; ++r) {
        u64 e = src[r];
        buf[base + r] = e;
        atomicAdd(&hist[(u32)(e >> 39) - BASE7], 1u);
      }
    }
    if (tid == 0) sh_cnt = 0;
    __syncthreads();  // gather + hist + cnt-init published

    suffix_select(hist, wsum, 0u, (u32)K1_, &sh_b1, &sh_base);
    // m >= K1_ guarantees sh_b1 >= 0
    const u32 T = ((u32)sh_b1 + BASE7) << 7;

    // compact survivors (k >= T; count m2 in [K1_, m]) into buf[2048..)
    for (u32 i = tid; i < m; i += bd) {
      u64 e = buf[i];
      if ((u32)(e >> 32) >= T) {
        u32 p = atomicAdd(&sh_cnt, 1u);
        buf[2048 + p] = e;
      }
    }
    __syncthreads();
    const u32 m2 = sh_cnt;

    u64* sbuf;
    u32 nn;
    if (m2 <= 1024u) {           // typical: ~1000-1010 survivors
      sbuf = buf + 2048;
      nn = 1024u;
      for (u32 i = (u32)tid; i < nn; i += bd)
        if (i >= m2) sbuf[i] = 0ull;
    } else {                     // pathological ties: sort the full set
      sbuf = buf;
      nn = next_pow2_ge(m, 1024u, (u32)CAP_C);
      for (u32 i = (u32)tid; i < nn; i += bd)
        if (i >= m) sbuf[i] = 0ull;
    }
    bitonic_sort_desc_ws(sbuf, nn, tid);  // opens+closes with barriers

    float os = -1.0f; int ooi = 0;
    if (tid < K1_) {
      u64 e = sbuf[tid];
      u32 k = (u32)(e >> 32);
      os = __uint_as_float(k);     // fast path: k != 0 always (s >= T0)
      ooi = (int)(~(u32)e);
      score1[slice * K1_ + tid] = os;
      idx1[slice * K1_ + tid] = ooi;
    }
    if (do_prep)
      prep_write(boxes + (size_t)(slice / C_) * N_ * 4, os, ooi, cor1,
                 (slice << 10) + tid);
    return;
  }

  // ---- exact fallback: two-level histogram select over the full column ----
  const int b = slice / C_, c = slice % C_;

  for (int i = tid; i < NBIN; i += bd) hist[i] = 0;
  __syncthreads();
  for (int i = tid; i < N_; i += bd) {
    float s = cls[((size_t)b * N_ + i) * C_ + c];
    if (s >= MIN_CONF_F) atomicAdd(&hist[__float_as_uint(s) >> 19], 1u);
  }
  __syncthreads();
  if (tid == 0) {
    u32 cum = 0; int b1 = -1; u32 base = 0;
    for (int bin = NBIN - 1; bin >= 0; --bin) {
      cum += hist[bin];
      if (cum >= (u32)K1_) { b1 = bin; base = cum - hist[bin]; break; }
    }
    sh_b1 = b1; sh_base = base;
    if (b1 < 0) sh_T = 0;
  }
  __syncthreads();
  const int b1 = sh_b1;

  if (b1 >= 0) {
    const u32 base = sh_base;
    for (int i = tid; i < NBIN; i += bd) hist[i] = 0;
    __syncthreads();
    for (int i = tid; i < N_; i += bd) {
      float s = cls[((size_t)b * N_ + i) * C_ + c];
      if (s >= MIN_CONF_F) {
        u32 k = __float_as_uint(s);
        if ((int)(k >> 19) == b1) atomicAdd(&hist[(k >> 7) & 0xFFFu], 1u);
      }
    }
    __syncthreads();
    if (tid == 0) {
      u32 cum = base;
      u32 T = ((u32)b1) << 19;
      for (int bin = NBIN - 1; bin >= 0; --bin) {
        cum += hist[bin];
        if (cum >= (u32)K1_) { T = (((u32)b1) << 19) | (((u32)bin) << 7); break; }
      }
      sh_T = T;
    }
    __syncthreads();
  }

  if (tid == 0) sh_cnt = 0;
  __syncthreads();
  const u32 T = sh_T;
  for (int i = tid; i < N_; i += bd) {
    float s = cls[((size_t)b * N_ + i) * C_ + c];
    if (s >= MIN_CONF_F) {
      u32 k = __float_as_uint(s);
      if (k >= T) {
        u32 pos = atomicAdd(&sh_cnt, 1u);
        if (pos < CAP) buf[pos] = ((u64)k << 32) | (u32)(~(u32)i);
      }
    }
  }
  __syncthreads();
  u32 mm = sh_cnt; if (mm > CAP) mm = CAP;
  for (int i = tid; i < CAP; i += bd)
    if ((u32)i >= mm) buf[i] = 0ull;
  __syncthreads();

  for (u32 kk = 2; kk <= CAP; kk <<= 1) {
    for (u32 j = kk >> 1; j > 0; j >>= 1) {
      for (u32 i = tid; i < CAP; i += bd) {
        u32 l = i ^ j;
        if (l > i) {
          u64 a = buf[i], bb2 = buf[l];
          bool desc = ((i & kk) == 0);
          if (desc ? (a < bb2) : (a > bb2)) { buf[i] = bb2; buf[l] = a; }
        }
      }
      __syncthreads();
    }
  }

  float os = -1.0f; int ooi = 0;
  if (tid < K1_) {
    u64 e = buf[tid];
    u32 k = (u32)(e >> 32);
    if (k != 0) { os = __uint_as_float(k); ooi = (int)(~(u32)e); }
    score1[slice * K1_ + tid] = os;
    idx1[slice * K1_ + tid] = ooi;
  }
  if (do_prep)
    prep_write(boxes + (size_t)(slice / C_) * N_ * 4, os, ooi, cor1,
               (slice << 10) + tid);
}

// ===========================================================================
// Split NMS: build (parallel across CUs) -> hierarchical scan. R4 verbatim.
// ===========================================================================
template <bool STRICT>
__global__ __launch_bounds__(256) void k_nms_build(const float4* __restrict__ cor,
                                                   float m1, float m0,
                                                   u64* __restrict__ maskg) {
  __shared__ float4 box4[1024];
  __shared__ float area[1024];
  const int blk = blockIdx.x;
  const int slice = blk / NB_;
  const int sub = blk - slice * NB_;
  const int tid = threadIdx.x, wave = tid >> 6, lane = tid & 63;

  for (int p = tid; p < 1024; p += 256) {
    const float4 c = cor[(slice << 10) + p];
    box4[p] = c;
    area[p] = (c.z - c.x) * (c.w - c.y);
  }
  __syncthreads();

  u64* mg = maskg + (size_t)slice * (NTILE * 64);

  for (int k = wave; k < TPB_; k += 4) {
    const int tt = sub * TPB_ + k;
    if (tt >= NTILE) break;
    build_tile<STRICT>(box4, area, tt, lane, m1, m0, mg);
  }
}

// Hierarchical scan core (rolled, O(1) registers). Exact greedy keep set.
__device__ void scan_core(const u64* __restrict__ mg, float s,
                          u64* __restrict__ keepb) {
  const int tid = threadIdx.x, wv = tid >> 6, lane = tid & 63;
  const u64 myvalid = __ballot(s >= MIN_CONF_F);

  u64 ext_partial = 0;

#pragma unroll 1
  for (int g = 0; g < 16; ++g) {
    u64 Tg = 0ull;
    if (g <= wv) Tg = mg[(TILE_ID(g, wv) << 6) + lane];
    const u64 nz = __ballot(Tg != 0ull);  // suppressor rows in this tile
    if (wv == g) {
      u64 ext = ext_partial;
      for (int off = 1; off < 64; off <<= 1) {
        u32 lo = (u32)__shfl_xor((int)(u32)ext, off, 64);
        u32 hi = (u32)__shfl_xor((int)(u32)(ext >> 32), off, 64);
        ext |= ((u64)hi << 32) | lo;
      }
      const u32 tlo = (u32)Tg, thi = (u32)(Tg >> 32);
      u64 rem = myvalid & ~ext;
      u64 cand = rem & nz;
      while (cand) {
        int i = __ffsll((long long)cand) - 1;
        cand &= cand - 1;  // clear bit i
        if ((rem >> i) & 1ull) {
          u32 rlo = __builtin_amdgcn_readlane(tlo, i);
          u32 rhi = __builtin_amdgcn_readlane(thi, i);
          u64 row = ((u64)rhi << 32) | rlo;  // bits only > i (diag-masked)
          rem &= ~row;
          cand &= ~row;
        }
      }
      if (lane == 0) keepb[g] = rem;
    }
    __syncthreads();
    if (wv > g) {
      u64 kg = keepb[g];  // broadcast LDS read
      if ((kg >> lane) & 1ull) ext_partial |= Tg;
    }
  }
}

// scan1 emits the keep BITMASK (16 u64 per slice): 97% less store traffic,
// and topk2's keep test becomes an LDS bit probe.
__global__ __launch_bounds__(1024) void k_nms_scan1(const u64* __restrict__ maskg,
                                                    const float* __restrict__ score1,
                                                    u64* __restrict__ keepbg) {
  __shared__ u64 keepb[16];
  const int slice = blockIdx.x;
  const int tid = threadIdx.x;
  float s = (tid < K1_) ? score1[slice * K1_ + tid] : -1.0f;
  scan_core(maskg + (size_t)slice * (NTILE * 64), s, keepb);
  __syncthreads();
  if (tid < 16) keepbg[slice * 16 + tid] = keepb[tid];
}

__global__ __launch_bounds__(1024) void k_nms_scan2(const u64* __restrict__ maskg,
                                                    const float* __restrict__ sel_score,
                                                    const int* __restrict__ sel_cls,
                                                    const int* __restrict__ sel_orig,
                                                    const float* __restrict__ boxes,
                                                    float* __restrict__ out) {
  __shared__ u64 keepb[16];
  __shared__ short ord[K1_];
  __shared__ int lbase[17];
  __shared__ int ordc;
  const int b = blockIdx.x;
  const int tid = threadIdx.x;
  float s = (tid < K1_) ? sel_score[b * K1_ + tid] : -1.0f;
  scan_core(maskg + (size_t)b * (NTILE * 64), s, keepb);
  __syncthreads();

  if (tid == 0) {
    int acc = 0;
    for (int wdx = 0; wdx < 16; ++wdx) {
      lbase[wdx] = acc;
      acc += __popcll(keepb[wdx]);
    }
    lbase[16] = acc;
    ordc = acc;
  }
  __syncthreads();
  if (tid < 16) {
    u64 m = keepb[tid];
    int base = lbase[tid];
    while (m) {
      int bit = __ffsll((long long)m) - 1;
      ord[base++] = (short)((tid << 6) | bit);
      m &= m - 1;
    }
  }
  __syncthreads();

  for (int t = tid; t < K1_ * 6; t += 1024) out[(size_t)b * K1_ * 6 + t] = 0.0f;
  __syncthreads();

  const int cnt = ordc;
  for (int q = tid; q < cnt; q += 1024) {
    int p = ord[q];
    int oi = sel_orig[b * K1_ + p];
    const float4 bp = *(const float4*)(boxes + ((size_t)b * N_ + oi) * 4);
    float* o = out + ((size_t)b * K1_ + q) * 6;
    o[0] = bp.x; o[1] = bp.y; o[2] = bp.z; o[3] = bp.w;
    o[4] = (float)sel_cls[b * K1_ + p];
    o[5] = sel_score[b * K1_ + p];
  }
}

// ---------------------------------------------------------------------------
// Kernel 3 (fast path): per-batch top-1000 over the C*K1 survivors (stable,
// flat-index tie-break). Keep set comes in as a BITMASK (160 u64 per batch)
// loaded once into LDS. Prep for pass-2 NMS fused as an epilogue.
// ---------------------------------------------------------------------------
__global__ __launch_bounds__(1024) void k_topk2(const float* __restrict__ score1,
                                                const int* __restrict__ idx1,
                                                const u64* __restrict__ keepbg,
                                                float* __restrict__ sel_score,
                                                int* __restrict__ sel_cls,
                                                int* __restrict__ sel_orig,
                                                const float* __restrict__ boxes,
                                                float4* __restrict__ cor2,
                                                int do_prep) {
  const int b = blockIdx.x;
  const int tid = threadIdx.x;

  __shared__ u32 hist[NBIN];
  __shared__ u32 wtot[16];
  __shared__ u64 buf[CAP];
  __shared__ u64 kmask[C_ * 16];  // batch b's keep bitmask (10 slices x 16)
  __shared__ int sh_bin;
  __shared__ u32 sh_next;
  __shared__ u32 sh_T, sh_cnt;

  if (tid < C_ * 16) kmask[tid] = keepbg[b * (C_ * 16) + tid];
  for (int i = tid; i < NBIN; i += 1024) hist[i] = 0;
  __syncthreads();

#define KEPT(f)                                                       \
  ({ u32 _cls = (u32)(f) / (u32)K1_;                                  \
     u32 _p = (u32)(f) - _cls * (u32)K1_;                             \
     (bool)((kmask[(_cls << 4) + (_p >> 6)] >> (_p & 63)) & 1ull); })

  for (int f = tid; f < N2_; f += 1024) {
    if (KEPT(f))
      atomicAdd(&hist[__float_as_uint(score1[b * N2_ + f]) >> 19], 1u);
  }
  __syncthreads();
  suffix_select(hist, wtot, 0u, (u32)K1_, &sh_bin, &sh_next);
  const int b1 = sh_bin;
  const u32 base = sh_next;

  if (b1 >= 0) {
    for (int i = tid; i < NBIN; i += 1024) hist[i] = 0;
    if (tid == 0) sh_bin = -2;
    __syncthreads();
    for (int f = tid; f < N2_; f += 1024) {
      if (KEPT(f)) {
        u32 k = __float_as_uint(score1[b * N2_ + f]);
        if ((int)(k >> 19) == b1) atomicAdd(&hist[(k >> 7) & 0xFFFu], 1u);
      }
    }
    __syncthreads();
    suffix_select(hist, wtot, base, (u32)K1_, &sh_bin, &sh_next);
    if (tid == 0) {
      int b2 = sh_bin;
      sh_T = (b2 >= 0) ? ((((u32)b1) << 19) | (((u32)b2) << 7))
                       : (((u32)b1) << 19);
    }
  } else {
    if (tid == 0) sh_T = 0;
  }
  if (tid == 0) sh_cnt = 0;
  __syncthreads();

  const u32 T = sh_T;
  for (int f = tid; f < N2_; f += 1024) {
    if (KEPT(f)) {
      u32 k = __float_as_uint(score1[b * N2_ + f]);
      if (k >= T) {
        u32 pos = atomicAdd(&sh_cnt, 1u);
        if (pos < CAP) buf[pos] = ((u64)k << 32) | (u32)(~(u32)f);
      }
    }
  }
#undef KEPT
  __syncthreads();
  u32 m = sh_cnt; if (m > CAP) m = CAP;
  const u32 n = next_pow2_ge(m, 1024u, (u32)CAP);
  for (u32 i = tid; i < n; i += 1024)
    if (i >= m) buf[i] = 0ull;
  bitonic_sort_desc_ws(buf, n, tid);

  float os = -1.0f; int ooi = 0;
  if (tid < K1_) {
    u64 e = buf[tid];
    u32 k = (u32)(e >> 32);
    float s; int cls, orig;
    if (k == 0) { s = -1.0f; cls = 0; orig = 0; }
    else {
      s = __uint_as_float(k);
      u32 f = ~(u32)e;
      cls = (int)(f / K1_);
      int slot = (int)(f - (u32)cls * K1_);
      orig = idx1[(b * C_ + cls) * K1_ + slot];
    }
    sel_score[b * K1_ + tid] = s;
    sel_cls[b * K1_ + tid] = cls;
    sel_orig[b * K1_ + tid] = orig;
    os = s; ooi = orig;
  }
  if (do_prep)
    prep_write(boxes + (size_t)b * N_ * 4, os, ooi, cor2, (b << 10) + tid);
}

// ===========================================================================
// Fallback path (ws too small) — validated R8 fused NMS + int-keep1 topk2.
// ===========================================================================
__device__ __forceinline__ void nms_run(const float* __restrict__ scores,
                                        const int* __restrict__ origs,
                                        const float* __restrict__ boxesB,
                                        float thr,
                                        float4* box4, float* area,
                                        u64* mask, u64* validw, u64* keepw) {
  const int tid = threadIdx.x;
  const int wave = tid >> 6, lane = tid & 63;

  {
    const int p = tid;
    float s = (p < K1_) ? scores[p] : -1.0f;
    bool v = (s >= MIN_CONF_F);
    float cx = 0.f, cy = 0.f, w = 0.f, h = 0.f;
    if (v) {
      const float4 bp = *(const float4*)(boxesB + (size_t)origs[p] * 4);
      cx = bp.x; cy = bp.y; w = bp.z; h = bp.w;
    }
    float y1 = cy - h * 0.5f, x1 = cx - w * 0.5f;
    float y2 = cy + h * 0.5f, x2 = cx + w * 0.5f;
    box4[p] = make_float4(y1, x1, y2, x2);
    area[p] = (y2 - y1) * (x2 - x1);
    u64 mb = __ballot(v);
    if (lane == 0) validw[wave] = mb;
  }
  __syncthreads();

  const float cf = thr;
  const float cnext = __uint_as_float(__float_as_uint(cf) + 1u);
  const double M = ((double)cf + (double)cnext) * 0.5;
  const bool strict = ((__float_as_uint(cf) & 1u) == 0u);

  const int ss = wave & 3, qq = wave >> 2;
  int col;
  if (qq == 0) col = ss;
  else if (qq == 1) col = 7 - ss;
  else if (qq == 2) col = 8 + ss;
  else col = 15 - ss;

  u64 vw = validw[tid & 15];
  u64 supp = 0;

  for (int seg = 0; seg < 4; ++seg) {
    const int ibase = seg * SEGROWS;
    const int lim = (K1_ - ibase < SEGROWS) ? (K1_ - ibase) : SEGROWS;
    const int rtg0 = ibase >> 6;
    int ntile = col - rtg0 + 1;
    if (ntile < 0) ntile = 0;
    if (ntile > 4) ntile = 4;

    if (ntile > 0) {
      float4 ib[4];
      float ia[4];
#pragma unroll
      for (int r = 0; r < 4; ++r) {
        if (r < ntile) {
          const int i = ibase + (r << 6) + lane;
          ib[r] = box4[i];
          ia[r] = area[i];
        }
      }
      u32 mhi[4] = {0, 0, 0, 0}, mlo[4] = {0, 0, 0, 0};
      const float4* jcol = &box4[col << 6];

      for (int j = 63; j >= 32; --j) {
        const float4 jb = jcol[j];
        const float ja = (jb.z - jb.x) * (jb.w - jb.y);
#pragma unroll
        for (int r = 0; r < 4; ++r) {
          if (r < ntile) {
            float ih = fminf(ib[r].z, jb.z) - fmaxf(ib[r].x, jb.x);
            ih = fmaxf(ih, 0.0f);
            float iw_ = fminf(ib[r].w, jb.w) - fmaxf(ib[r].y, jb.y);
            iw_ = fmaxf(iw_, 0.0f);
            float inter = ih * iw_;
            float den = fmaxf((ia[r] + ja) - inter, 1e-8f);
            bool p_ = strict ? ((double)inter > M * (double)den)
                             : ((double)inter >= M * (double)den);
            mhi[r] = (mhi[r] << 1) | (p_ ? 1u : 0u);
          }
        }
      }
      for (int j = 31; j >= 0; --j) {
        const float4 jb = jcol[j];
        const float ja = (jb.z - jb.x) * (jb.w - jb.y);
#pragma unroll
        for (int r = 0; r < 4; ++r) {
          if (r < ntile) {
            float ih = fminf(ib[r].z, jb.z) - fmaxf(ib[r].x, jb.x);
            ih = fmaxf(ih, 0.0f);
            float iw_ = fminf(ib[r].w, jb.w) - fmaxf(ib[r].y, jb.y);
            iw_ = fmaxf(iw_, 0.0f);
            float inter = ih * iw_;
            float den = fmaxf((ia[r] + ja) - inter, 1e-8f);
            bool p_ = strict ? ((double)inter > M * (double)den)
                             : ((double)inter >= M * (double)den);
            mlo[r] = (mlo[r] << 1) | (p_ ? 1u : 0u);
          }
        }
      }
#pragma unroll
      for (int r = 0; r < 4; ++r) {
        if (r < ntile) {
          u64 m = ((u64)mhi[r] << 32) | (u64)mlo[r];
          if (rtg0 + r == col)
            m &= (lane == 63) ? 0ull : (~0ull << (lane + 1));
          const int il = (r << 6) | lane;
          mask[il * 16 + (col ^ (il & 15))] = m;
        }
      }
    }
    __syncthreads();

    if (tid < 64) {
      const int l = tid & 15;
      u64 r0 = 0, r1 = 0, r2 = 0, r3 = 0;
      if (l >= ((ibase + 0) >> 6)) r0 = mask[0 * 16 + (l ^ 0)];
      if (l >= ((ibase + 1) >> 6)) r1 = mask[1 * 16 + (l ^ 1)];
      if (l >= ((ibase + 2) >> 6)) r2 = mask[2 * 16 + (l ^ 2)];
      if (l >= ((ibase + 3) >> 6)) r3 = mask[3 * 16 + (l ^ 3)];
      for (int il = 0; il < lim; il += 4) {
        const int i0 = ibase + il;
        const int n0 = (il + 4 < lim) ? il + 4 : il;
        const int n1 = (il + 5 < lim) ? il + 5 : il;
        const int n2 = (il + 6 < lim) ? il + 6 : il;
        const int n3 = (il + 7 < lim) ? il + 7 : il;
        u64 m0 = r0, m1 = r1, m2 = r2, m3 = r3;
        r0 = (l >= ((ibase + n0) >> 6)) ? mask[n0 * 16 + (l ^ (n0 & 15))] : 0ull;
        r1 = (l >= ((ibase + n1) >> 6)) ? mask[n1 * 16 + (l ^ (n1 & 15))] : 0ull;
        r2 = (l >= ((ibase + n2) >> 6)) ? mask[n2 * 16 + (l ^ (n2 & 15))] : 0ull;
        r3 = (l >= ((ibase + n3) >> 6)) ? mask[n3 * 16 + (l ^ (n3 & 15))] : 0ull;
        bool a;
        a = (tid == (i0 >> 6)) && (((vw & ~supp) >> (i0 & 63)) & 1ull);
        if (__any(a)) supp |= m0;
        a = (tid == ((i0 + 1) >> 6)) && (((vw & ~supp) >> ((i0 + 1) & 63)) & 1ull);
        if (__any(a)) supp |= m1;
        a = (tid == ((i0 + 2) >> 6)) && (((vw & ~supp) >> ((i0 + 2) & 63)) & 1ull);
        if (__any(a)) supp |= m2;
        a = (tid == ((i0 + 3) >> 6)) && (((vw & ~supp) >> ((i0 + 3) & 63)) & 1ull);
        if (__any(a)) supp |= m3;
      }
    }
    __syncthreads();
  }

  if (tid < 16) keepw[tid] = vw & ~supp;
}

__global__ __launch_bounds__(1024) void k_nms1(const float* __restrict__ boxes,
                                               const float* __restrict__ score1,
                                               const int* __restrict__ idx1,
                                               int* __restrict__ keep1) {
  __shared__ float4 box4[1024];
  __shared__ float area[1024];
  __shared__ u64 mask[SEGROWS * 16];
  __shared__ u64 validw[16], keepw[16];

  const int slice = blockIdx.x;
  const int b = slice / C_;
  nms_run(score1 + slice * K1_, idx1 + slice * K1_,
          boxes + (size_t)b * N_ * 4, NMS_IOU_F,
          box4, area, mask, validw, keepw);
  __syncthreads();

  const int p = threadIdx.x;
  if (p < K1_)
    keep1[slice * K1_ + p] = (int)((keepw[p >> 6] >> (p & 63)) & 1ull);
}

__global__ __launch_bounds__(1024) void k_topk2_fb(const float* __restrict__ score1,
                                                   const int* __restrict__ idx1,
                                                   const int* __restrict__ keep1,
                                                   float* __restrict__ sel_score,
                                                   int* __restrict__ sel_cls,
                                                   int* __restrict__ sel_orig) {
  const int b = blockIdx.x;
  const int tid = threadIdx.x;

  __shared__ u32 hist[NBIN];
  __shared__ u32 wtot[16];
  __shared__ u64 buf[CAP];
  __shared__ int sh_bin;
  __shared__ u32 sh_next;
  __shared__ u32 sh_T, sh_cnt;

  for (int i = tid; i < NBIN; i += 1024) hist[i] = 0;
  __syncthreads();
  for (int f = tid; f < N2_; f += 1024) {
    if (keep1[b * N2_ + f])
      atomicAdd(&hist[__float_as_uint(score1[b * N2_ + f]) >> 19], 1u);
  }
  __syncthreads();
  suffix_select(hist, wtot, 0u, (u32)K1_, &sh_bin, &sh_next);
  const int b1 = sh_bin;
  const u32 base = sh_next;

  if (b1 >= 0) {
    for (int i = tid; i < NBIN; i += 1024) hist[i] = 0;
    if (tid == 0) sh_bin = -2;
    __syncthreads();
    for (int f = tid; f < N2_; f += 1024) {
      if (keep1[b * N2_ + f]) {
        u32 k = __float_as_uint(score1[b * N2_ + f]);
        if ((int)(k >> 19) == b1) atomicAdd(&hist[(k >> 7) & 0xFFFu], 1u);
      }
    }
    __syncthreads();
    suffix_select(hist, wtot, base, (u32)K1_, &sh_bin, &sh_next);
    if (tid == 0) {
      int b2 = sh_bin;
      sh_T = (b2 >= 0) ? ((((u32)b1) << 19) | (((u32)b2) << 7))
                       : (((u32)b1) << 19);
    }
  } else {
    if (tid == 0) sh_T = 0;
  }
  if (tid == 0) sh_cnt = 0;
  __syncthreads();

  const u32 T = sh_T;
  for (int f = tid; f < N2_; f += 1024) {
    if (keep1[b * N2_ + f]) {
      u32 k = __float_as_uint(score1[b * N2_ + f]);
      if (k >= T) {
        u32 pos = atomicAdd(&sh_cnt, 1u);
        if (pos < CAP) buf[pos] = ((u64)k << 32) | (u32)(~(u32)f);
      }
    }
  }
  __syncthreads();
  u32 m = sh_cnt; if (m > CAP) m = CAP;
  const u32 n = next_pow2_ge(m, 1024u, (u32)CAP);
  for (u32 i = tid; i < n; i += 1024)
    if (i >= m) buf[i] = 0ull;
  bitonic_sort_desc_ws(buf, n, tid);

  if (tid < K1_) {
    u64 e = buf[tid];
    u32 k = (u32)(e >> 32);
    float s; int cls, orig;
    if (k == 0) { s = -1.0f; cls = 0; orig = 0; }
    else {
      s = __uint_as_float(k);
      u32 f = ~(u32)e;
      cls = (int)(f / K1_);
      int slot = (int)(f - (u32)cls * K1_);
      orig = idx1[(b * C_ + cls) * K1_ + slot];
    }
    sel_score[b * K1_ + tid] = s;
    sel_cls[b * K1_ + tid] = cls;
    sel_orig[b * K1_ + tid] = orig;
  }
}

__global__ __launch_bounds__(1024) void k_nms2_out(const float* __restrict__ boxes,
                                                   const float* __restrict__ sel_score,
                                                   const int* __restrict__ sel_cls,
                                                   const int* __restrict__ sel_orig,
                                                   float* __restrict__ out) {
  __shared__ float4 box4[1024];
  __shared__ float area[1024];
  __shared__ u64 mask[SEGROWS * 16];
  __shared__ u64 validw[16], keepw[16];
  __shared__ short ord[K1_];
  __shared__ int lbase[17];
  __shared__ int ordc;

  const int b = blockIdx.x;
  const int tid = threadIdx.x;
  nms_run(sel_score + b * K1_, sel_orig + b * K1_,
          boxes + (size_t)b * N_ * 4, POST_IOU_F,
          box4, area, mask, validw, keepw);
  __syncthreads();

  if (tid == 0) {
    int acc = 0;
    for (int wdx = 0; wdx < 16; ++wdx) {
      lbase[wdx] = acc;
      acc += __popcll(keepw[wdx]);
    }
    lbase[16] = acc;
    ordc = acc;
  }
  __syncthreads();
  if (tid < 16) {
    u64 m = keepw[tid];
    int base = lbase[tid];
    while (m) {
      int bit = __ffsll((long long)m) - 1;
      ord[base++] = (short)((tid << 6) | bit);
      m &= m - 1;
    }
  }
  __syncthreads();

  for (int t = tid; t < K1_ * 6; t += 1024) out[(size_t)b * K1_ * 6 + t] = 0.0f;
  __syncthreads();

  const int cnt = ordc;
  for (int q = tid; q < cnt; q += 1024) {
    int p = ord[q];
    int oi = sel_orig[b * K1_ + p];
    const float4 bp = *(const float4*)(boxes + ((size_t)b * N_ + oi) * 4);
    float* o = out + ((size_t)b * K1_ + q) * 6;
    o[0] = bp.x; o[1] = bp.y; o[2] = bp.z; o[3] = bp.w;
    o[4] = (float)sel_cls[b * K1_ + p];
    o[5] = sel_score[b * K1_ + p];
  }
}

// ---------------------------------------------------------------------------
static inline void m_split(float cf, float* m1, float* m0, bool* strict) {
  u32 b; memcpy(&b, &cf, 4);
  u32 nb = b + 1; float cn; memcpy(&cn, &nb, 4);
  double M = ((double)cf + (double)cn) * 0.5;
  *m1 = (float)M;
  *m0 = (float)(M - (double)*m1);
  *strict = ((b & 1u) == 0u);
}

extern "C" void kernel_launch(void* const* d_in, const int* in_sizes, int n_in,
                              void* d_out, int out_size, void* d_ws, size_t ws_size,
                              hipStream_t stream) {
  const float* cls = (const float*)d_in[0];    // (8,100000,10) f32
  const float* boxes = (const float*)d_in[1];  // (8,100000,4)  f32
  float* out = (float*)d_out;                  // (8,1000,6)    f32

  char* ws = (char*)d_ws;
  float* score1    = (float*)(ws);                     // 80000 f32
  int*   idx1      = (int*)(ws + 320000);              // 80000 i32
  int*   keep1     = (int*)(ws + 640000);              // fallback: 80000 i32
  u64*   keepbg    = (u64*)(ws + 640000);              // fast: 80*16 u64 (same region)
  float* sel_score = (float*)(ws + 960000);            // 8000 f32
  int*   sel_cls   = (int*)(ws + 992000);              // 8000 i32
  int*   sel_orig  = (int*)(ws + 1024000);             // 8000 i32
  u32*   hdr       = (u32*)(ws + 1056000);             // 512*84 u32   -> 1228032
  u64*   cand      = (u64*)(ws + 1228032);             // 512*512 u64  -> 3325184
  u64*   mask1     = (u64*)(ws + 3325184);             // 80*8704 u64  -> 8895744
  u64*   mask2     = (u64*)(ws + 3325184);             // aliases mask1 (dead before reuse)
  float4* cor1     = (float4*)(ws + 8895744);          // 80*1024 f4   -> 10206464
  float4* cor2     = (float4*)(ws + 8895744);          // aliases cor1 (dead before reuse)
  const size_t WS_NEED = 10206464;

  const int do_fast = (ws_size >= WS_NEED) ? 1 : 0;

  float m1a, m0a, m1b, m0b; bool sa, sb;
  m_split(NMS_IOU_F, &m1a, &m0a, &sa);   // 0.4f  -> strict = false
  m_split(POST_IOU_F, &m1b, &m0b, &sb);  // 0.65f -> strict = true

  hipLaunchKernelGGL(k_compact, dim3(CBLK), dim3(256), 0, stream,
                     cls, cand, hdr);
  hipLaunchKernelGGL(k_sel, dim3(B_ * C_), dim3(1024), 0, stream,
                     cls, cand, hdr, score1, idx1, boxes, cor1, do_fast);

  if (do_fast) {
    if (sa)
      hipLaunchKernelGGL(k_nms_build<true>, dim3(B_ * C_ * NB_), dim3(256), 0,
                         stream, cor1, m1a, m0a, mask1);
    else
      hipLaunchKernelGGL(k_nms_build<false>, dim3(B_ * C_ * NB_), dim3(256), 0,
                         stream, cor1, m1a, m0a, mask1);
    hipLaunchKernelGGL(k_nms_scan1, dim3(B_ * C_), dim3(1024), 0, stream,
                       mask1, score1, keepbg);
    hipLaunchKernelGGL(k_topk2, dim3(B_), dim3(1024), 0, stream,
                       score1, idx1, keepbg, sel_score, sel_cls, sel_orig,
                       boxes, cor2, 1);
    if (sb)
      hipLaunchKernelGGL(k_nms_build<true>, dim3(B_ * NB_), dim3(256), 0,
                         stream, cor2, m1b, m0b, mask2);
    else
      hipLaunchKernelGGL(k_nms_build<false>, dim3(B_ * NB_), dim3(256), 0,
                         stream, cor2, m1b, m0b, mask2);
    hipLaunchKernelGGL(k_nms_scan2, dim3(B_), dim3(1024), 0, stream,
                       mask2, sel_score, sel_cls, sel_orig, boxes, out);
  } else {
    hipLaunchKernelGGL(k_nms1, dim3(B_ * C_), dim3(1024), 0, stream,
                       boxes, score1, idx1, keep1);
    hipLaunchKernelGGL(k_topk2_fb, dim3(B_), dim3(1024), 0, stream,
                       score1, idx1, keep1, sel_score, sel_cls, sel_orig);
    hipLaunchKernelGGL(k_nms2_out, dim3(B_), dim3(1024), 0, stream,
                       boxes, sel_score, sel_cls, sel_orig, out);
  }
}